// Round 1
// baseline (1124.581 us; speedup 1.0000x reference)
//
#include <hip/hip_runtime.h>
#include <math.h>

#define B_SZ   8
#define E_DIM  256
#define L_SEQ  4096
#define S_TOP  256
#define NHEAD  8
#define HD     32
#define NSPLIT 4   // s-splits in distance kernel

// ---------------------------------------------------------------------------
// K0: gather query subset  qs_pack[b][e][s] = query[b][e][ind[b][s]]
// ---------------------------------------------------------------------------
__global__ __launch_bounds__(256) void k_gather(const float* __restrict__ query,
                                                const int* __restrict__ ind,
                                                float* __restrict__ qs_pack) {
    int t = blockIdx.x * 256 + threadIdx.x;     // over B*E*S = 524288
    int s = t & (S_TOP - 1);
    int e = (t >> 8) & (E_DIM - 1);
    int b = t >> 16;
    int idx = ind[b * S_TOP + s];
    qs_pack[t] = query[((size_t)b * E_DIM + e) * L_SEQ + idx];
}

// ---------------------------------------------------------------------------
// K1: min over s-range of L1 distance key[l] vs query-subset[s]
// grid (L/256, NSPLIT, B), block 256. Thread owns one key token l.
// qs values are wave-uniform -> s_load; accumulate fp32 chunks into f64.
// ---------------------------------------------------------------------------
__global__ __launch_bounds__(256) void k_dist(const float* __restrict__ keys,
                                              const float* __restrict__ qs_pack,
                                              double* __restrict__ minpart) {
    const int b  = blockIdx.z;
    const int ss = blockIdx.y;                  // s range [ss*64, ss*64+64)
    const int l  = blockIdx.x * 256 + threadIdx.x;
    const float* kb = keys + (size_t)b * E_DIM * L_SEQ + l;
    const float* qb = qs_pack + (size_t)b * E_DIM * S_TOP;
    double md = 1e300;
    for (int sg = 0; sg < 2; ++sg) {            // 2 groups of 32 s
        const int sbase = ss * 64 + sg * 32;
        double dd[32];
#pragma unroll
        for (int j = 0; j < 32; ++j) dd[j] = 0.0;
        for (int ec = 0; ec < E_DIM; ec += 32) {
            float ca[32];
#pragma unroll
            for (int j = 0; j < 32; ++j) ca[j] = 0.f;
#pragma unroll 4
            for (int e = ec; e < ec + 32; ++e) {
                const float kv = kb[(size_t)e * L_SEQ];
                const float* qp = qb + e * S_TOP + sbase;   // wave-uniform
#pragma unroll
                for (int j = 0; j < 32; ++j) ca[j] += fabsf(kv - qp[j]);
            }
#pragma unroll
            for (int j = 0; j < 32; ++j) dd[j] += (double)ca[j];
        }
#pragma unroll
        for (int j = 0; j < 32; ++j) md = fmin(md, dd[j]);
    }
    minpart[((size_t)(b * NSPLIT + ss)) * L_SEQ + l] = md;
}

// ---------------------------------------------------------------------------
// K2: combine split-mins, rank each token, emit selected indices (rank<256).
// Exact f64 compares with index tie-break == lax.top_k stable semantics.
// grid (L/256, B), block 256
// ---------------------------------------------------------------------------
__global__ __launch_bounds__(256) void k_rank(const double* __restrict__ minpart,
                                              int* __restrict__ sel) {
    const int b = blockIdx.y;
    const int l = blockIdx.x * 256 + threadIdx.x;
    __shared__ double sd[L_SEQ];                // 32 KiB
    const double* mp = minpart + (size_t)b * NSPLIT * L_SEQ;
    for (int j = threadIdx.x; j < L_SEQ; j += 256) {
        double v = mp[j];
        v = fmin(v, mp[L_SEQ + j]);
        v = fmin(v, mp[2 * L_SEQ + j]);
        v = fmin(v, mp[3 * L_SEQ + j]);
        sd[j] = v;
    }
    __syncthreads();
    const double dl = sd[l];
    int rank = 0;
#pragma unroll 4
    for (int j = 0; j < L_SEQ; ++j) {
        double dj = sd[j];
        rank += (dj < dl) || (dj == dl && j < l) ? 1 : 0;
    }
    if (rank < S_TOP) sel[b * S_TOP + rank] = l;
}

// ---------------------------------------------------------------------------
// K3: gather + project selected keys/values: dst[b][k][f] =
//     sum_e src[b][e][sel[k]] * W[f][e] + bias[f]
// grid (E/64, S_TOP/64, B), block (16,16), 4x4 micro-tile
// ---------------------------------------------------------------------------
__global__ __launch_bounds__(256) void k_kvproj(const float* __restrict__ src,
                                                const int* __restrict__ sel,
                                                const float* __restrict__ W,
                                                const float* __restrict__ bias,
                                                float* __restrict__ dst) {
    const int b  = blockIdx.z;
    const int f0 = blockIdx.x * 64;
    const int k0 = blockIdx.y * 64;
    const int tx = threadIdx.x, ty = threadIdx.y;
    const int lid = ty * 16 + tx;
    __shared__ float As[16][68];
    __shared__ float Ws[16][68];
    float c[4][4] = {};
    const float* sb = src + (size_t)b * E_DIM * L_SEQ;
    const int* selb = sel + b * S_TOP;
    for (int e0 = 0; e0 < E_DIM; e0 += 16) {
        {   // As[e][k] gather (scattered loads)
            int e  = lid >> 4;
            int k4 = (lid & 15) * 4;
#pragma unroll
            for (int c2 = 0; c2 < 4; ++c2) {
                int kk = k4 + c2;
                As[e][kk] = sb[(size_t)(e0 + e) * L_SEQ + selb[k0 + kk]];
            }
        }
        {   // Ws[e][f] from row-major W[f][e] (coalesced float4 along e)
            int f  = lid >> 2;
            int e4 = (lid & 3) * 4;
            float4 w = *(const float4*)(W + (size_t)(f0 + f) * E_DIM + e0 + e4);
            Ws[e4 + 0][f] = w.x; Ws[e4 + 1][f] = w.y;
            Ws[e4 + 2][f] = w.z; Ws[e4 + 3][f] = w.w;
        }
        __syncthreads();
#pragma unroll
        for (int e = 0; e < 16; ++e) {
            float4 a = *(const float4*)&As[e][ty * 4];
            float4 w = *(const float4*)&Ws[e][tx * 4];
            float av[4] = {a.x, a.y, a.z, a.w};
            float wv[4] = {w.x, w.y, w.z, w.w};
#pragma unroll
            for (int i = 0; i < 4; ++i)
#pragma unroll
                for (int j = 0; j < 4; ++j) c[i][j] += av[i] * wv[j];
        }
        __syncthreads();
    }
#pragma unroll
    for (int i = 0; i < 4; ++i) {
        float4 o;
        o.x = c[i][0] + bias[f0 + tx * 4 + 0];
        o.y = c[i][1] + bias[f0 + tx * 4 + 1];
        o.z = c[i][2] + bias[f0 + tx * 4 + 2];
        o.w = c[i][3] + bias[f0 + tx * 4 + 3];
        *(float4*)(dst + ((size_t)b * S_TOP + k0 + ty * 4 + i) * E_DIM + f0 + tx * 4) = o;
    }
}

// ---------------------------------------------------------------------------
// K3q: Q projection: qh[b][l][f] = scale*(sum_e query[b][e][l]*Wq[f][e] + bq[f])
// A is [e][l] in global (already "transposed") -> coalesced along l.
// grid (E/64, L/64, B), block (16,16)
// ---------------------------------------------------------------------------
__global__ __launch_bounds__(256) void k_qproj(const float* __restrict__ query,
                                               const float* __restrict__ W,
                                               const float* __restrict__ bias,
                                               float* __restrict__ qh,
                                               float scale) {
    const int b  = blockIdx.z;
    const int f0 = blockIdx.x * 64;
    const int l0 = blockIdx.y * 64;
    const int tx = threadIdx.x, ty = threadIdx.y;
    const int lid = ty * 16 + tx;
    __shared__ float As[16][68];
    __shared__ float Ws[16][68];
    float c[4][4] = {};
    const float* sb = query + (size_t)b * E_DIM * L_SEQ;
    for (int e0 = 0; e0 < E_DIM; e0 += 16) {
        {   // As[e][l] direct coalesced float4
            int e  = lid >> 4;
            int l4 = (lid & 15) * 4;
            float4 a = *(const float4*)(sb + (size_t)(e0 + e) * L_SEQ + l0 + l4);
            *(float4*)&As[e][l4] = a;
        }
        {
            int f  = lid >> 2;
            int e4 = (lid & 3) * 4;
            float4 w = *(const float4*)(W + (size_t)(f0 + f) * E_DIM + e0 + e4);
            Ws[e4 + 0][f] = w.x; Ws[e4 + 1][f] = w.y;
            Ws[e4 + 2][f] = w.z; Ws[e4 + 3][f] = w.w;
        }
        __syncthreads();
#pragma unroll
        for (int e = 0; e < 16; ++e) {
            float4 a = *(const float4*)&As[e][ty * 4];
            float4 w = *(const float4*)&Ws[e][tx * 4];
            float av[4] = {a.x, a.y, a.z, a.w};
            float wv[4] = {w.x, w.y, w.z, w.w};
#pragma unroll
            for (int i = 0; i < 4; ++i)
#pragma unroll
                for (int j = 0; j < 4; ++j) c[i][j] += av[i] * wv[j];
        }
        __syncthreads();
    }
#pragma unroll
    for (int i = 0; i < 4; ++i) {
        float4 o;
        o.x = scale * (c[i][0] + bias[f0 + tx * 4 + 0]);
        o.y = scale * (c[i][1] + bias[f0 + tx * 4 + 1]);
        o.z = scale * (c[i][2] + bias[f0 + tx * 4 + 2]);
        o.w = scale * (c[i][3] + bias[f0 + tx * 4 + 3]);
        *(float4*)(qh + ((size_t)b * L_SEQ + l0 + ty * 4 + i) * E_DIM + f0 + tx * 4) = o;
    }
}

// ---------------------------------------------------------------------------
// K4: fused attention per (b,h): scores=qh.kh, online softmax, o=attn.vh
// kh/vh rows are wave-uniform -> s_load. grid (L/256, H, B), block 256.
// ---------------------------------------------------------------------------
__global__ __launch_bounds__(256) void k_attn(const float* __restrict__ qh,
                                              const float* __restrict__ kh,
                                              const float* __restrict__ vh,
                                              float* __restrict__ ob) {
    const int b = blockIdx.z, h = blockIdx.y;
    const int l = blockIdx.x * 256 + threadIdx.x;
    const float* qp = qh + ((size_t)b * L_SEQ + l) * E_DIM + h * HD;
    float4 q[8];
#pragma unroll
    for (int j = 0; j < 8; ++j) q[j] = *(const float4*)(qp + 4 * j);
    float m = -INFINITY, ssum = 0.f;
    float o[HD];
#pragma unroll
    for (int d = 0; d < HD; ++d) o[d] = 0.f;
    const float* khb = kh + (size_t)b * S_TOP * E_DIM + h * HD;
    const float* vhb = vh + (size_t)b * S_TOP * E_DIM + h * HD;
    for (int kc = 0; kc < S_TOP; kc += 8) {
        float s[8];
#pragma unroll
        for (int i = 0; i < 8; ++i) {
            const float* kr = khb + (size_t)(kc + i) * E_DIM;  // wave-uniform
            float acc = 0.f;
#pragma unroll
            for (int j = 0; j < 8; ++j) {
                acc += q[j].x * kr[4 * j + 0] + q[j].y * kr[4 * j + 1]
                     + q[j].z * kr[4 * j + 2] + q[j].w * kr[4 * j + 3];
            }
            s[i] = acc;
        }
        float cm = s[0];
#pragma unroll
        for (int i = 1; i < 8; ++i) cm = fmaxf(cm, s[i]);
        float nm = fmaxf(m, cm);
        float rf = __expf(m - nm);          // m=-inf -> 0 on first chunk
        float p[8];
        float ps = 0.f;
#pragma unroll
        for (int i = 0; i < 8; ++i) { p[i] = __expf(s[i] - nm); ps += p[i]; }
        ssum = ssum * rf + ps;
#pragma unroll
        for (int d = 0; d < HD; ++d) o[d] *= rf;
#pragma unroll
        for (int i = 0; i < 8; ++i) {
            const float* vr = vhb + (size_t)(kc + i) * E_DIM;  // wave-uniform
#pragma unroll
            for (int d = 0; d < HD; ++d) o[d] += p[i] * vr[d];
        }
        m = nm;
    }
    const float inv = 1.0f / ssum;
    float* op = ob + ((size_t)b * L_SEQ + l) * E_DIM + h * HD;
#pragma unroll
    for (int j = 0; j < 8; ++j) {
        float4 v;
        v.x = o[4 * j + 0] * inv; v.y = o[4 * j + 1] * inv;
        v.z = o[4 * j + 2] * inv; v.w = o[4 * j + 3] * inv;
        *(float4*)(op + 4 * j) = v;
    }
}

// ---------------------------------------------------------------------------
// K5: out projection + transpose store: out[b][f][l] =
//     sum_e o[b][l][e]*Wout[f][e] + bo[f]
// grid (L/64, E/64, B), block (16,16)
// ---------------------------------------------------------------------------
__global__ __launch_bounds__(256) void k_outproj(const float* __restrict__ ob,
                                                 const float* __restrict__ W,
                                                 const float* __restrict__ bias,
                                                 float* __restrict__ out) {
    const int b  = blockIdx.z;
    const int l0 = blockIdx.x * 64;
    const int f0 = blockIdx.y * 64;
    const int tx = threadIdx.x, ty = threadIdx.y;
    const int lid = ty * 16 + tx;
    __shared__ float As[16][68];
    __shared__ float Ws[16][68];
    float c[4][4] = {};
    const float* sb = ob + (size_t)b * L_SEQ * E_DIM;
    for (int e0 = 0; e0 < E_DIM; e0 += 16) {
        {   // transpose-load o[l][e] -> As[e][l]
            int ll = lid >> 2;
            int e4 = (lid & 3) * 4;
            float4 a = *(const float4*)(sb + (size_t)(l0 + ll) * E_DIM + e0 + e4);
            As[e4 + 0][ll] = a.x; As[e4 + 1][ll] = a.y;
            As[e4 + 2][ll] = a.z; As[e4 + 3][ll] = a.w;
        }
        {
            int f  = lid >> 2;
            int e4 = (lid & 3) * 4;
            float4 w = *(const float4*)(W + (size_t)(f0 + f) * E_DIM + e0 + e4);
            Ws[e4 + 0][f] = w.x; Ws[e4 + 1][f] = w.y;
            Ws[e4 + 2][f] = w.z; Ws[e4 + 3][f] = w.w;
        }
        __syncthreads();
#pragma unroll
        for (int e = 0; e < 16; ++e) {
            float4 a = *(const float4*)&As[e][tx * 4];   // along l
            float4 w = *(const float4*)&Ws[e][ty * 4];   // along f
            float av[4] = {a.x, a.y, a.z, a.w};
            float wv[4] = {w.x, w.y, w.z, w.w};
#pragma unroll
            for (int i = 0; i < 4; ++i)
#pragma unroll
                for (int j = 0; j < 4; ++j) c[i][j] += wv[i] * av[j];
        }
        __syncthreads();
    }
#pragma unroll
    for (int i = 0; i < 4; ++i) {
        const int f = f0 + ty * 4 + i;
        const float bv = bias[f];
        float4 o;
        o.x = c[i][0] + bv; o.y = c[i][1] + bv;
        o.z = c[i][2] + bv; o.w = c[i][3] + bv;
        *(float4*)(out + ((size_t)b * E_DIM + f) * L_SEQ + l0 + tx * 4) = o;
    }
}

// ---------------------------------------------------------------------------
extern "C" void kernel_launch(void* const* d_in, const int* in_sizes, int n_in,
                              void* d_out, int out_size, void* d_ws, size_t ws_size,
                              hipStream_t stream) {
    const float* query = (const float*)d_in[0];
    const float* keys  = (const float*)d_in[1];
    const float* vals  = (const float*)d_in[2];
    const int*   rind  = (const int*)d_in[3];
    const float* ipw   = (const float*)d_in[4];
    const float* ipb   = (const float*)d_in[5];
    const float* opw   = (const float*)d_in[6];
    const float* opb   = (const float*)d_in[7];
    float* out = (float*)d_out;

    char* ws = (char*)d_ws;
    float*  qs_pack = (float*)(ws + 0);                       //  2 MiB
    double* minpart = (double*)(ws + (size_t)2  * 1024 * 1024); // 1 MiB
    int*    sel     = (int*)   (ws + (size_t)3  * 1024 * 1024); // 8 KiB
    float*  kh      = (float*) (ws + (size_t)4  * 1024 * 1024); // 2 MiB
    float*  vh      = (float*) (ws + (size_t)6  * 1024 * 1024); // 2 MiB
    float*  qh      = (float*) (ws + (size_t)8  * 1024 * 1024); // 32 MiB
    float*  obuf    = (float*) (ws + (size_t)40 * 1024 * 1024); // 32 MiB

    const float scale = 0.17677669529663687f;  // 32^-0.5

    k_gather<<<dim3((B_SZ * E_DIM * S_TOP) / 256), 256, 0, stream>>>(query, rind, qs_pack);
    k_dist<<<dim3(L_SEQ / 256, NSPLIT, B_SZ), 256, 0, stream>>>(keys, qs_pack, minpart);
    k_rank<<<dim3(L_SEQ / 256, B_SZ), 256, 0, stream>>>(minpart, sel);
    k_kvproj<<<dim3(E_DIM / 64, S_TOP / 64, B_SZ), dim3(16, 16), 0, stream>>>(
        keys, sel, ipw + (size_t)E_DIM * E_DIM, ipb + E_DIM, kh);
    k_kvproj<<<dim3(E_DIM / 64, S_TOP / 64, B_SZ), dim3(16, 16), 0, stream>>>(
        vals, sel, ipw + (size_t)2 * E_DIM * E_DIM, ipb + 2 * E_DIM, vh);
    k_qproj<<<dim3(E_DIM / 64, L_SEQ / 64, B_SZ), dim3(16, 16), 0, stream>>>(
        query, ipw, ipb, qh, scale);
    k_attn<<<dim3(L_SEQ / 256, NHEAD, B_SZ), 256, 0, stream>>>(qh, kh, vh, obuf);
    k_outproj<<<dim3(L_SEQ / 64, E_DIM / 64, B_SZ), dim3(16, 16), 0, stream>>>(
        obuf, opw, opb, out);
}

// Round 2
// 1035.621 us; speedup vs baseline: 1.0859x; 1.0859x over previous
//
#include <hip/hip_runtime.h>
#include <math.h>

#define B_SZ   8
#define E_DIM  256
#define L_SEQ  4096
#define S_TOP  256
#define NHEAD  8
#define HD     32
#define NSPLIT 4   // s-splits in distance kernel

// ---------------------------------------------------------------------------
// K0: gather query subset  qs_pack[b][e][s] = query[b][e][ind[b][s]]
// ---------------------------------------------------------------------------
__global__ __launch_bounds__(256) void k_gather(const float* __restrict__ query,
                                                const int* __restrict__ ind,
                                                float* __restrict__ qs_pack) {
    int t = blockIdx.x * 256 + threadIdx.x;     // over B*E*S = 524288
    int s = t & (S_TOP - 1);
    int e = (t >> 8) & (E_DIM - 1);
    int b = t >> 16;
    int idx = ind[b * S_TOP + s];
    qs_pack[t] = query[((size_t)b * E_DIM + e) * L_SEQ + idx];
}

// ---------------------------------------------------------------------------
// K1: min over s-range of L1 distance key[l] vs query-subset[s]
// grid (L/256, NSPLIT, B), block 256. Thread owns one key token l.
// 16-s groups: dd[16] f64 + ca[16] f32 ≈ 70 VGPR -> no scratch spill
// (round-1 dd[32]/ca[32] spilled: VGPR_Count=56 < live state, 358us).
// Numerics bit-identical to round 1: fp32 accumulate per 32-e chunk,
// fold each chunk into f64, exact f64 min.
// ---------------------------------------------------------------------------
__global__ __launch_bounds__(256) void k_dist(const float* __restrict__ keys,
                                              const float* __restrict__ qs_pack,
                                              double* __restrict__ minpart) {
    const int b  = blockIdx.z;
    const int ss = blockIdx.y;                  // s range [ss*64, ss*64+64)
    const int l  = blockIdx.x * 256 + threadIdx.x;
    const float* kb = keys + (size_t)b * E_DIM * L_SEQ + l;
    const float* qb = qs_pack + (size_t)b * E_DIM * S_TOP;
    double md = 1e300;
    for (int sg = 0; sg < 4; ++sg) {            // 4 groups of 16 s
        const int sbase = ss * 64 + sg * 16;
        double dd[16];
#pragma unroll
        for (int j = 0; j < 16; ++j) dd[j] = 0.0;
        for (int ec = 0; ec < E_DIM; ec += 32) {
            float ca[16];
#pragma unroll
            for (int j = 0; j < 16; ++j) ca[j] = 0.f;
#pragma unroll 4
            for (int e = ec; e < ec + 32; ++e) {
                const float kv = kb[(size_t)e * L_SEQ];
                const float* qp = qb + e * S_TOP + sbase;   // wave-uniform
#pragma unroll
                for (int j = 0; j < 16; ++j) ca[j] += fabsf(kv - qp[j]);
            }
#pragma unroll
            for (int j = 0; j < 16; ++j) dd[j] += (double)ca[j];
        }
#pragma unroll
        for (int j = 0; j < 16; ++j) md = fmin(md, dd[j]);
    }
    minpart[((size_t)(b * NSPLIT + ss)) * L_SEQ + l] = md;
}

// ---------------------------------------------------------------------------
// K2: combine split-mins, rank each token, emit selected indices (rank<256).
// Exact f64 compares with index tie-break == lax.top_k stable semantics.
// grid (L/256, B), block 256
// ---------------------------------------------------------------------------
__global__ __launch_bounds__(256) void k_rank(const double* __restrict__ minpart,
                                              int* __restrict__ sel) {
    const int b = blockIdx.y;
    const int l = blockIdx.x * 256 + threadIdx.x;
    __shared__ double sd[L_SEQ];                // 32 KiB
    const double* mp = minpart + (size_t)b * NSPLIT * L_SEQ;
    for (int j = threadIdx.x; j < L_SEQ; j += 256) {
        double v = mp[j];
        v = fmin(v, mp[L_SEQ + j]);
        v = fmin(v, mp[2 * L_SEQ + j]);
        v = fmin(v, mp[3 * L_SEQ + j]);
        sd[j] = v;
    }
    __syncthreads();
    const double dl = sd[l];
    int rank = 0;
#pragma unroll 4
    for (int j = 0; j < L_SEQ; ++j) {
        double dj = sd[j];
        rank += (dj < dl) || (dj == dl && j < l) ? 1 : 0;
    }
    if (rank < S_TOP) sel[b * S_TOP + rank] = l;
}

// ---------------------------------------------------------------------------
// K3: gather + project selected keys/values: dst[b][k][f] =
//     sum_e src[b][e][sel[k]] * W[f][e] + bias[f]
// grid (E/64, S_TOP/64, B), block (16,16), 4x4 micro-tile
// ---------------------------------------------------------------------------
__global__ __launch_bounds__(256) void k_kvproj(const float* __restrict__ src,
                                                const int* __restrict__ sel,
                                                const float* __restrict__ W,
                                                const float* __restrict__ bias,
                                                float* __restrict__ dst) {
    const int b  = blockIdx.z;
    const int f0 = blockIdx.x * 64;
    const int k0 = blockIdx.y * 64;
    const int tx = threadIdx.x, ty = threadIdx.y;
    const int lid = ty * 16 + tx;
    __shared__ float As[16][68];
    __shared__ float Ws[16][68];
    float c[4][4] = {};
    const float* sb = src + (size_t)b * E_DIM * L_SEQ;
    const int* selb = sel + b * S_TOP;
    for (int e0 = 0; e0 < E_DIM; e0 += 16) {
        {   // As[e][k] gather (scattered loads)
            int e  = lid >> 4;
            int k4 = (lid & 15) * 4;
#pragma unroll
            for (int c2 = 0; c2 < 4; ++c2) {
                int kk = k4 + c2;
                As[e][kk] = sb[(size_t)(e0 + e) * L_SEQ + selb[k0 + kk]];
            }
        }
        {   // Ws[e][f] from row-major W[f][e] (coalesced float4 along e)
            int f  = lid >> 2;
            int e4 = (lid & 3) * 4;
            float4 w = *(const float4*)(W + (size_t)(f0 + f) * E_DIM + e0 + e4);
            Ws[e4 + 0][f] = w.x; Ws[e4 + 1][f] = w.y;
            Ws[e4 + 2][f] = w.z; Ws[e4 + 3][f] = w.w;
        }
        __syncthreads();
#pragma unroll
        for (int e = 0; e < 16; ++e) {
            float4 a = *(const float4*)&As[e][ty * 4];
            float4 w = *(const float4*)&Ws[e][tx * 4];
            float av[4] = {a.x, a.y, a.z, a.w};
            float wv[4] = {w.x, w.y, w.z, w.w};
#pragma unroll
            for (int i = 0; i < 4; ++i)
#pragma unroll
                for (int j = 0; j < 4; ++j) c[i][j] += av[i] * wv[j];
        }
        __syncthreads();
    }
#pragma unroll
    for (int i = 0; i < 4; ++i) {
        float4 o;
        o.x = c[i][0] + bias[f0 + tx * 4 + 0];
        o.y = c[i][1] + bias[f0 + tx * 4 + 1];
        o.z = c[i][2] + bias[f0 + tx * 4 + 2];
        o.w = c[i][3] + bias[f0 + tx * 4 + 3];
        *(float4*)(dst + ((size_t)b * S_TOP + k0 + ty * 4 + i) * E_DIM + f0 + tx * 4) = o;
    }
}

// ---------------------------------------------------------------------------
// K3q: Q projection: qh[b][l][f] = scale*(sum_e query[b][e][l]*Wq[f][e] + bq[f])
// grid (E/64, L/64, B), block (16,16)
// ---------------------------------------------------------------------------
__global__ __launch_bounds__(256) void k_qproj(const float* __restrict__ query,
                                               const float* __restrict__ W,
                                               const float* __restrict__ bias,
                                               float* __restrict__ qh,
                                               float scale) {
    const int b  = blockIdx.z;
    const int f0 = blockIdx.x * 64;
    const int l0 = blockIdx.y * 64;
    const int tx = threadIdx.x, ty = threadIdx.y;
    const int lid = ty * 16 + tx;
    __shared__ float As[16][68];
    __shared__ float Ws[16][68];
    float c[4][4] = {};
    const float* sb = query + (size_t)b * E_DIM * L_SEQ;
    for (int e0 = 0; e0 < E_DIM; e0 += 16) {
        {   // As[e][l] direct coalesced float4
            int e  = lid >> 4;
            int l4 = (lid & 15) * 4;
            float4 a = *(const float4*)(sb + (size_t)(e0 + e) * L_SEQ + l0 + l4);
            *(float4*)&As[e][l4] = a;
        }
        {
            int f  = lid >> 2;
            int e4 = (lid & 3) * 4;
            float4 w = *(const float4*)(W + (size_t)(f0 + f) * E_DIM + e0 + e4);
            Ws[e4 + 0][f] = w.x; Ws[e4 + 1][f] = w.y;
            Ws[e4 + 2][f] = w.z; Ws[e4 + 3][f] = w.w;
        }
        __syncthreads();
#pragma unroll
        for (int e = 0; e < 16; ++e) {
            float4 a = *(const float4*)&As[e][ty * 4];
            float4 w = *(const float4*)&Ws[e][tx * 4];
            float av[4] = {a.x, a.y, a.z, a.w};
            float wv[4] = {w.x, w.y, w.z, w.w};
#pragma unroll
            for (int i = 0; i < 4; ++i)
#pragma unroll
                for (int j = 0; j < 4; ++j) c[i][j] += av[i] * wv[j];
        }
        __syncthreads();
    }
#pragma unroll
    for (int i = 0; i < 4; ++i) {
        float4 o;
        o.x = scale * (c[i][0] + bias[f0 + tx * 4 + 0]);
        o.y = scale * (c[i][1] + bias[f0 + tx * 4 + 1]);
        o.z = scale * (c[i][2] + bias[f0 + tx * 4 + 2]);
        o.w = scale * (c[i][3] + bias[f0 + tx * 4 + 3]);
        *(float4*)(qh + ((size_t)b * L_SEQ + l0 + ty * 4 + i) * E_DIM + f0 + tx * 4) = o;
    }
}

// ---------------------------------------------------------------------------
// K4: fused attention per (b,h). Round-2 change: stage K/V head tile in LDS
// (64 KiB), all lanes read the same row address -> bank broadcast. Removes
// the round-1 SGPR pressure (112 SGPR, lgkm serialization, 358us).
// grid (L/256, H, B), block 256, one query per thread.
// ---------------------------------------------------------------------------
__global__ __launch_bounds__(256) void k_attn(const float* __restrict__ qh,
                                              const float* __restrict__ kh,
                                              const float* __restrict__ vh,
                                              float* __restrict__ ob) {
    __shared__ float ks[S_TOP][HD];             // 32 KiB
    __shared__ float vs[S_TOP][HD];             // 32 KiB
    const int b = blockIdx.z, h = blockIdx.y;
    const int tid = threadIdx.x;
    const int l = blockIdx.x * 256 + tid;
    const float* khb = kh + (size_t)b * S_TOP * E_DIM + h * HD;
    const float* vhb = vh + (size_t)b * S_TOP * E_DIM + h * HD;
#pragma unroll
    for (int t = tid; t < S_TOP * 8; t += 256) {
        const int row = t >> 3;
        const int j = (t & 7) * 4;
        *(float4*)&ks[row][j] = *(const float4*)(khb + (size_t)row * E_DIM + j);
        *(float4*)&vs[row][j] = *(const float4*)(vhb + (size_t)row * E_DIM + j);
    }
    const float* qp = qh + ((size_t)b * L_SEQ + l) * E_DIM + h * HD;
    float4 q[8];
#pragma unroll
    for (int j = 0; j < 8; ++j) q[j] = *(const float4*)(qp + 4 * j);
    __syncthreads();

    float m = -INFINITY, ssum = 0.f;
    float o[HD];
#pragma unroll
    for (int d = 0; d < HD; ++d) o[d] = 0.f;
    for (int kc = 0; kc < S_TOP; kc += 8) {
        float s[8];
#pragma unroll
        for (int i = 0; i < 8; ++i) {
            float acc = 0.f;
#pragma unroll
            for (int j = 0; j < 8; ++j) {
                float4 kv = *(const float4*)&ks[kc + i][4 * j];  // broadcast
                acc += q[j].x * kv.x + q[j].y * kv.y
                     + q[j].z * kv.z + q[j].w * kv.w;
            }
            s[i] = acc;
        }
        float cm = s[0];
#pragma unroll
        for (int i = 1; i < 8; ++i) cm = fmaxf(cm, s[i]);
        float nm = fmaxf(m, cm);
        float rf = __expf(m - nm);          // m=-inf -> 0 on first chunk
        float p[8];
        float ps = 0.f;
#pragma unroll
        for (int i = 0; i < 8; ++i) { p[i] = __expf(s[i] - nm); ps += p[i]; }
        ssum = ssum * rf + ps;
#pragma unroll
        for (int d = 0; d < HD; ++d) o[d] *= rf;
#pragma unroll
        for (int i = 0; i < 8; ++i) {
#pragma unroll
            for (int j = 0; j < 8; ++j) {
                float4 vv = *(const float4*)&vs[kc + i][4 * j];  // broadcast
                o[4 * j + 0] += p[i] * vv.x;
                o[4 * j + 1] += p[i] * vv.y;
                o[4 * j + 2] += p[i] * vv.z;
                o[4 * j + 3] += p[i] * vv.w;
            }
        }
        m = nm;
    }
    const float inv = 1.0f / ssum;
    float* op = ob + ((size_t)b * L_SEQ + l) * E_DIM + h * HD;
#pragma unroll
    for (int j = 0; j < 8; ++j) {
        float4 v;
        v.x = o[4 * j + 0] * inv; v.y = o[4 * j + 1] * inv;
        v.z = o[4 * j + 2] * inv; v.w = o[4 * j + 3] * inv;
        *(float4*)(op + 4 * j) = v;
    }
}

// ---------------------------------------------------------------------------
// K5: out projection + transpose store: out[b][f][l] =
//     sum_e o[b][l][e]*Wout[f][e] + bo[f]
// grid (L/64, E/64, B), block (16,16)
// ---------------------------------------------------------------------------
__global__ __launch_bounds__(256) void k_outproj(const float* __restrict__ ob,
                                                 const float* __restrict__ W,
                                                 const float* __restrict__ bias,
                                                 float* __restrict__ out) {
    const int b  = blockIdx.z;
    const int l0 = blockIdx.x * 64;
    const int f0 = blockIdx.y * 64;
    const int tx = threadIdx.x, ty = threadIdx.y;
    const int lid = ty * 16 + tx;
    __shared__ float As[16][68];
    __shared__ float Ws[16][68];
    float c[4][4] = {};
    const float* sb = ob + (size_t)b * L_SEQ * E_DIM;
    for (int e0 = 0; e0 < E_DIM; e0 += 16) {
        {   // transpose-load o[l][e] -> As[e][l]
            int ll = lid >> 2;
            int e4 = (lid & 3) * 4;
            float4 a = *(const float4*)(sb + (size_t)(l0 + ll) * E_DIM + e0 + e4);
            As[e4 + 0][ll] = a.x; As[e4 + 1][ll] = a.y;
            As[e4 + 2][ll] = a.z; As[e4 + 3][ll] = a.w;
        }
        {
            int f  = lid >> 2;
            int e4 = (lid & 3) * 4;
            float4 w = *(const float4*)(W + (size_t)(f0 + f) * E_DIM + e0 + e4);
            Ws[e4 + 0][f] = w.x; Ws[e4 + 1][f] = w.y;
            Ws[e4 + 2][f] = w.z; Ws[e4 + 3][f] = w.w;
        }
        __syncthreads();
#pragma unroll
        for (int e = 0; e < 16; ++e) {
            float4 a = *(const float4*)&As[e][tx * 4];   // along l
            float4 w = *(const float4*)&Ws[e][ty * 4];   // along f
            float av[4] = {a.x, a.y, a.z, a.w};
            float wv[4] = {w.x, w.y, w.z, w.w};
#pragma unroll
            for (int i = 0; i < 4; ++i)
#pragma unroll
                for (int j = 0; j < 4; ++j) c[i][j] += wv[i] * av[j];
        }
        __syncthreads();
    }
#pragma unroll
    for (int i = 0; i < 4; ++i) {
        const int f = f0 + ty * 4 + i;
        const float bv = bias[f];
        float4 o;
        o.x = c[i][0] + bv; o.y = c[i][1] + bv;
        o.z = c[i][2] + bv; o.w = c[i][3] + bv;
        *(float4*)(out + ((size_t)b * E_DIM + f) * L_SEQ + l0 + tx * 4) = o;
    }
}

// ---------------------------------------------------------------------------
extern "C" void kernel_launch(void* const* d_in, const int* in_sizes, int n_in,
                              void* d_out, int out_size, void* d_ws, size_t ws_size,
                              hipStream_t stream) {
    const float* query = (const float*)d_in[0];
    const float* keys  = (const float*)d_in[1];
    const float* vals  = (const float*)d_in[2];
    const int*   rind  = (const int*)d_in[3];
    const float* ipw   = (const float*)d_in[4];
    const float* ipb   = (const float*)d_in[5];
    const float* opw   = (const float*)d_in[6];
    const float* opb   = (const float*)d_in[7];
    float* out = (float*)d_out;

    char* ws = (char*)d_ws;
    float*  qs_pack = (float*)(ws + 0);                       //  2 MiB
    double* minpart = (double*)(ws + (size_t)2  * 1024 * 1024); // 1 MiB
    int*    sel     = (int*)   (ws + (size_t)3  * 1024 * 1024); // 8 KiB
    float*  kh      = (float*) (ws + (size_t)4  * 1024 * 1024); // 2 MiB
    float*  vh      = (float*) (ws + (size_t)6  * 1024 * 1024); // 2 MiB
    float*  qh      = (float*) (ws + (size_t)8  * 1024 * 1024); // 32 MiB
    float*  obuf    = (float*) (ws + (size_t)40 * 1024 * 1024); // 32 MiB

    const float scale = 0.17677669529663687f;  // 32^-0.5

    k_gather<<<dim3((B_SZ * E_DIM * S_TOP) / 256), 256, 0, stream>>>(query, rind, qs_pack);
    k_dist<<<dim3(L_SEQ / 256, NSPLIT, B_SZ), 256, 0, stream>>>(keys, qs_pack, minpart);
    k_rank<<<dim3(L_SEQ / 256, B_SZ), 256, 0, stream>>>(minpart, sel);
    k_kvproj<<<dim3(E_DIM / 64, S_TOP / 64, B_SZ), dim3(16, 16), 0, stream>>>(
        keys, sel, ipw + (size_t)E_DIM * E_DIM, ipb + E_DIM, kh);
    k_kvproj<<<dim3(E_DIM / 64, S_TOP / 64, B_SZ), dim3(16, 16), 0, stream>>>(
        vals, sel, ipw + (size_t)2 * E_DIM * E_DIM, ipb + 2 * E_DIM, vh);
    k_qproj<<<dim3(E_DIM / 64, L_SEQ / 64, B_SZ), dim3(16, 16), 0, stream>>>(
        query, ipw, ipb, qh, scale);
    k_attn<<<dim3(L_SEQ / 256, NHEAD, B_SZ), 256, 0, stream>>>(qh, kh, vh, obuf);
    k_outproj<<<dim3(L_SEQ / 64, E_DIM / 64, B_SZ), dim3(16, 16), 0, stream>>>(
        obuf, opw, opb, out);
}

// Round 3
// 828.520 us; speedup vs baseline: 1.3573x; 1.2500x over previous
//
#include <hip/hip_runtime.h>
#include <math.h>

#define B_SZ   8
#define E_DIM  256
#define L_SEQ  4096
#define S_TOP  256
#define NHEAD  8
#define HD     32
#define NSPLIT 4   // s-blocks in distance kernel (S_TOP/64)

// ---------------------------------------------------------------------------
// K0: gather query subset  qs_pack[b][e][s] = query[b][e][ind[b][s]]
// ---------------------------------------------------------------------------
__global__ __launch_bounds__(256) void k_gather(const float* __restrict__ query,
                                                const int* __restrict__ ind,
                                                float* __restrict__ qs_pack) {
    int t = blockIdx.x * 256 + threadIdx.x;     // over B*E*S = 524288
    int s = t & (S_TOP - 1);
    int e = (t >> 8) & (E_DIM - 1);
    int b = t >> 16;
    int idx = ind[b * S_TOP + s];
    qs_pack[t] = query[((size_t)b * E_DIM + e) * L_SEQ + idx];
}

// ---------------------------------------------------------------------------
// K1 (round-3 rewrite): tiled LDS "GEMM-style" L1-distance + min.
// dist(l,s) = sum_e |key[e][l] - qs[e][s]|, min over the 64-s slice.
// grid (L/64, S/64, B), block (16,16), 4x4 micro-tile per thread.
// Rounds 1-2 were latency-bound: serial s_load chain + 512-block grid
// (25% occupancy cap) + scratch traffic from ~32 live 64-bit global
// addresses (FETCH_SIZE 79GB vs 0.6GB genuine). This structure stages via
// one float4/thread/tile and reads ds_read_b128: 2 LDS reads per 32 VALU.
// Numerics bit-identical to rounds 1-2: fp32 sum over 32-e chunks in
// ascending e order, chunks folded into f64 ascending, exact f64 min.
// ---------------------------------------------------------------------------
__global__ __launch_bounds__(256) void k_dist(const float* __restrict__ keys,
                                              const float* __restrict__ qs_pack,
                                              double* __restrict__ minpart) {
    const int b  = blockIdx.z;
    const int ss = blockIdx.y;                  // s-slice [ss*64, ss*64+64)
    const int l0 = blockIdx.x * 64;
    const int tx = threadIdx.x, ty = threadIdx.y;
    const int lid = ty * 16 + tx;
    __shared__ float Ks[16][68];                // [e][l]
    __shared__ float Qs[16][68];                // [e][s]
    __shared__ double red[64][17];              // final cross-ty min
    const float* kb = keys + (size_t)b * E_DIM * L_SEQ;
    const float* qb = qs_pack + (size_t)b * E_DIM * S_TOP + ss * 64;

    float  c[4][4];                             // fp32 sum within 32-e chunk
    double d[4][4];                             // exact f64 chunk accumulator
#pragma unroll
    for (int i = 0; i < 4; ++i)
#pragma unroll
        for (int j = 0; j < 4; ++j) d[i][j] = 0.0;

    for (int e0 = 0; e0 < E_DIM; e0 += 16) {
        __syncthreads();
        {   // stage Ks[e][l]: coalesced float4 along l
            int e  = lid >> 4;
            int l4 = (lid & 15) * 4;
            *(float4*)&Ks[e][l4] = *(const float4*)(kb + (size_t)(e0 + e) * L_SEQ + l0 + l4);
            *(float4*)&Qs[e][l4] = *(const float4*)(qb + (size_t)(e0 + e) * S_TOP + l4);
        }
        __syncthreads();
        if ((e0 & 16) == 0) {
#pragma unroll
            for (int i = 0; i < 4; ++i)
#pragma unroll
                for (int j = 0; j < 4; ++j) c[i][j] = 0.f;
        }
#pragma unroll
        for (int e = 0; e < 16; ++e) {
            float4 kv = *(const float4*)&Ks[e][tx * 4];
            float4 qv = *(const float4*)&Qs[e][ty * 4];
            float kvv[4] = {kv.x, kv.y, kv.z, kv.w};
            float qvv[4] = {qv.x, qv.y, qv.z, qv.w};
#pragma unroll
            for (int i = 0; i < 4; ++i)
#pragma unroll
                for (int j = 0; j < 4; ++j) c[i][j] += fabsf(qvv[i] - kvv[j]);
        }
        if ((e0 & 16) == 16) {                  // fold completed 32-e chunk
#pragma unroll
            for (int i = 0; i < 4; ++i)
#pragma unroll
                for (int j = 0; j < 4; ++j) d[i][j] += (double)c[i][j];
        }
    }
    // per-thread min over its 4 s values, per l column
    double dmin[4];
#pragma unroll
    for (int j = 0; j < 4; ++j) {
        double m = d[0][j];
        m = fmin(m, d[1][j]); m = fmin(m, d[2][j]); m = fmin(m, d[3][j]);
        dmin[j] = m;
    }
    __syncthreads();
#pragma unroll
    for (int j = 0; j < 4; ++j) red[tx * 4 + j][ty] = dmin[j];
    __syncthreads();
    if (lid < 64) {
        double m = red[lid][0];
#pragma unroll
        for (int t = 1; t < 16; ++t) m = fmin(m, red[lid][t]);
        minpart[((size_t)(b * NSPLIT + ss)) * L_SEQ + l0 + lid] = m;
    }
}

// ---------------------------------------------------------------------------
// K2: combine split-mins, rank each token, emit selected indices (rank<256).
// Exact f64 compares with index tie-break == lax.top_k stable semantics.
// grid (L/256, B), block 256
// ---------------------------------------------------------------------------
__global__ __launch_bounds__(256) void k_rank(const double* __restrict__ minpart,
                                              int* __restrict__ sel) {
    const int b = blockIdx.y;
    const int l = blockIdx.x * 256 + threadIdx.x;
    __shared__ double sd[L_SEQ];                // 32 KiB
    const double* mp = minpart + (size_t)b * NSPLIT * L_SEQ;
    for (int j = threadIdx.x; j < L_SEQ; j += 256) {
        double v = mp[j];
        v = fmin(v, mp[L_SEQ + j]);
        v = fmin(v, mp[2 * L_SEQ + j]);
        v = fmin(v, mp[3 * L_SEQ + j]);
        sd[j] = v;
    }
    __syncthreads();
    const double dl = sd[l];
    int rank = 0;
#pragma unroll 4
    for (int j = 0; j < L_SEQ; ++j) {
        double dj = sd[j];
        rank += (dj < dl) || (dj == dl && j < l) ? 1 : 0;
    }
    if (rank < S_TOP) sel[b * S_TOP + rank] = l;
}

// ---------------------------------------------------------------------------
// K3: gather + project selected keys/values: dst[b][k][f] =
//     sum_e src[b][e][sel[k]] * W[f][e] + bias[f]
// grid (E/64, S_TOP/64, B), block (16,16), 4x4 micro-tile
// ---------------------------------------------------------------------------
__global__ __launch_bounds__(256) void k_kvproj(const float* __restrict__ src,
                                                const int* __restrict__ sel,
                                                const float* __restrict__ W,
                                                const float* __restrict__ bias,
                                                float* __restrict__ dst) {
    const int b  = blockIdx.z;
    const int f0 = blockIdx.x * 64;
    const int k0 = blockIdx.y * 64;
    const int tx = threadIdx.x, ty = threadIdx.y;
    const int lid = ty * 16 + tx;
    __shared__ float As[16][68];
    __shared__ float Ws[16][68];
    float c[4][4] = {};
    const float* sb = src + (size_t)b * E_DIM * L_SEQ;
    const int* selb = sel + b * S_TOP;
    for (int e0 = 0; e0 < E_DIM; e0 += 16) {
        {   // As[e][k] gather (scattered loads)
            int e  = lid >> 4;
            int k4 = (lid & 15) * 4;
#pragma unroll
            for (int c2 = 0; c2 < 4; ++c2) {
                int kk = k4 + c2;
                As[e][kk] = sb[(size_t)(e0 + e) * L_SEQ + selb[k0 + kk]];
            }
        }
        {   // Ws[e][f] from row-major W[f][e] (coalesced float4 along e)
            int f  = lid >> 2;
            int e4 = (lid & 3) * 4;
            float4 w = *(const float4*)(W + (size_t)(f0 + f) * E_DIM + e0 + e4);
            Ws[e4 + 0][f] = w.x; Ws[e4 + 1][f] = w.y;
            Ws[e4 + 2][f] = w.z; Ws[e4 + 3][f] = w.w;
        }
        __syncthreads();
#pragma unroll
        for (int e = 0; e < 16; ++e) {
            float4 a = *(const float4*)&As[e][ty * 4];
            float4 w = *(const float4*)&Ws[e][tx * 4];
            float av[4] = {a.x, a.y, a.z, a.w};
            float wv[4] = {w.x, w.y, w.z, w.w};
#pragma unroll
            for (int i = 0; i < 4; ++i)
#pragma unroll
                for (int j = 0; j < 4; ++j) c[i][j] += av[i] * wv[j];
        }
        __syncthreads();
    }
#pragma unroll
    for (int i = 0; i < 4; ++i) {
        float4 o;
        o.x = c[i][0] + bias[f0 + tx * 4 + 0];
        o.y = c[i][1] + bias[f0 + tx * 4 + 1];
        o.z = c[i][2] + bias[f0 + tx * 4 + 2];
        o.w = c[i][3] + bias[f0 + tx * 4 + 3];
        *(float4*)(dst + ((size_t)b * S_TOP + k0 + ty * 4 + i) * E_DIM + f0 + tx * 4) = o;
    }
}

// ---------------------------------------------------------------------------
// K3q: Q projection: qh[b][l][f] = scale*(sum_e query[b][e][l]*Wq[f][e] + bq[f])
// grid (E/64, L/64, B), block (16,16)
// ---------------------------------------------------------------------------
__global__ __launch_bounds__(256) void k_qproj(const float* __restrict__ query,
                                               const float* __restrict__ W,
                                               const float* __restrict__ bias,
                                               float* __restrict__ qh,
                                               float scale) {
    const int b  = blockIdx.z;
    const int f0 = blockIdx.x * 64;
    const int l0 = blockIdx.y * 64;
    const int tx = threadIdx.x, ty = threadIdx.y;
    const int lid = ty * 16 + tx;
    __shared__ float As[16][68];
    __shared__ float Ws[16][68];
    float c[4][4] = {};
    const float* sb = query + (size_t)b * E_DIM * L_SEQ;
    for (int e0 = 0; e0 < E_DIM; e0 += 16) {
        {   // As[e][l] direct coalesced float4
            int e  = lid >> 4;
            int l4 = (lid & 15) * 4;
            float4 a = *(const float4*)(sb + (size_t)(e0 + e) * L_SEQ + l0 + l4);
            *(float4*)&As[e][l4] = a;
        }
        {
            int f  = lid >> 2;
            int e4 = (lid & 3) * 4;
            float4 w = *(const float4*)(W + (size_t)(f0 + f) * E_DIM + e0 + e4);
            Ws[e4 + 0][f] = w.x; Ws[e4 + 1][f] = w.y;
            Ws[e4 + 2][f] = w.z; Ws[e4 + 3][f] = w.w;
        }
        __syncthreads();
#pragma unroll
        for (int e = 0; e < 16; ++e) {
            float4 a = *(const float4*)&As[e][ty * 4];
            float4 w = *(const float4*)&Ws[e][tx * 4];
            float av[4] = {a.x, a.y, a.z, a.w};
            float wv[4] = {w.x, w.y, w.z, w.w};
#pragma unroll
            for (int i = 0; i < 4; ++i)
#pragma unroll
                for (int j = 0; j < 4; ++j) c[i][j] += av[i] * wv[j];
        }
        __syncthreads();
    }
#pragma unroll
    for (int i = 0; i < 4; ++i) {
        float4 o;
        o.x = scale * (c[i][0] + bias[f0 + tx * 4 + 0]);
        o.y = scale * (c[i][1] + bias[f0 + tx * 4 + 1]);
        o.z = scale * (c[i][2] + bias[f0 + tx * 4 + 2]);
        o.w = scale * (c[i][3] + bias[f0 + tx * 4 + 3]);
        *(float4*)(qh + ((size_t)b * L_SEQ + l0 + ty * 4 + i) * E_DIM + f0 + tx * 4) = o;
    }
}

// ---------------------------------------------------------------------------
// K4: fused attention per (b,h). Round-3 change: TWO queries per thread so
// each ds_read_b128 of K/V feeds 8 FMAs instead of 4 (kernel was
// LDS-pipe-bound). grid (L/512, H, B), block 256.
// ---------------------------------------------------------------------------
__global__ __launch_bounds__(256) void k_attn(const float* __restrict__ qh,
                                              const float* __restrict__ kh,
                                              const float* __restrict__ vh,
                                              float* __restrict__ ob) {
    __shared__ float ks[S_TOP][HD];             // 32 KiB
    __shared__ float vs[S_TOP][HD];             // 32 KiB
    const int b = blockIdx.z, h = blockIdx.y;
    const int tid = threadIdx.x;
    const int la = blockIdx.x * 512 + tid;      // query A; query B = la+256
    const float* khb = kh + (size_t)b * S_TOP * E_DIM + h * HD;
    const float* vhb = vh + (size_t)b * S_TOP * E_DIM + h * HD;
#pragma unroll
    for (int t = tid; t < S_TOP * 8; t += 256) {
        const int row = t >> 3;
        const int j = (t & 7) * 4;
        *(float4*)&ks[row][j] = *(const float4*)(khb + (size_t)row * E_DIM + j);
        *(float4*)&vs[row][j] = *(const float4*)(vhb + (size_t)row * E_DIM + j);
    }
    const float* qpa = qh + ((size_t)b * L_SEQ + la) * E_DIM + h * HD;
    float4 qa[8], qb4[8];
#pragma unroll
    for (int j = 0; j < 8; ++j) {
        qa[j]  = *(const float4*)(qpa + 4 * j);
        qb4[j] = *(const float4*)(qpa + 256 * E_DIM + 4 * j);
    }
    __syncthreads();

    float ma = -INFINITY, mb = -INFINITY, ssa = 0.f, ssb = 0.f;
    float oa[HD], obv[HD];
#pragma unroll
    for (int d = 0; d < HD; ++d) { oa[d] = 0.f; obv[d] = 0.f; }
    for (int kc = 0; kc < S_TOP; kc += 8) {
        float sa[8], sb[8];
#pragma unroll
        for (int i = 0; i < 8; ++i) {
            float acca = 0.f, accb = 0.f;
#pragma unroll
            for (int j = 0; j < 8; ++j) {
                float4 kv = *(const float4*)&ks[kc + i][4 * j];  // broadcast
                acca += qa[j].x  * kv.x + qa[j].y  * kv.y
                      + qa[j].z  * kv.z + qa[j].w  * kv.w;
                accb += qb4[j].x * kv.x + qb4[j].y * kv.y
                      + qb4[j].z * kv.z + qb4[j].w * kv.w;
            }
            sa[i] = acca; sb[i] = accb;
        }
        float cma = sa[0], cmb = sb[0];
#pragma unroll
        for (int i = 1; i < 8; ++i) { cma = fmaxf(cma, sa[i]); cmb = fmaxf(cmb, sb[i]); }
        float nma = fmaxf(ma, cma), nmb = fmaxf(mb, cmb);
        float rfa = __expf(ma - nma), rfb = __expf(mb - nmb);
        float pa[8], pb[8];
        float psa = 0.f, psb = 0.f;
#pragma unroll
        for (int i = 0; i < 8; ++i) {
            pa[i] = __expf(sa[i] - nma); psa += pa[i];
            pb[i] = __expf(sb[i] - nmb); psb += pb[i];
        }
        ssa = ssa * rfa + psa;  ssb = ssb * rfb + psb;
#pragma unroll
        for (int d = 0; d < HD; ++d) { oa[d] *= rfa; obv[d] *= rfb; }
#pragma unroll
        for (int i = 0; i < 8; ++i) {
#pragma unroll
            for (int j = 0; j < 8; ++j) {
                float4 vv = *(const float4*)&vs[kc + i][4 * j];  // broadcast
                oa[4 * j + 0]  += pa[i] * vv.x;  obv[4 * j + 0] += pb[i] * vv.x;
                oa[4 * j + 1]  += pa[i] * vv.y;  obv[4 * j + 1] += pb[i] * vv.y;
                oa[4 * j + 2]  += pa[i] * vv.z;  obv[4 * j + 2] += pb[i] * vv.z;
                oa[4 * j + 3]  += pa[i] * vv.w;  obv[4 * j + 3] += pb[i] * vv.w;
            }
        }
        ma = nma; mb = nmb;
    }
    const float inva = 1.0f / ssa, invb = 1.0f / ssb;
    float* opa = ob + ((size_t)b * L_SEQ + la) * E_DIM + h * HD;
#pragma unroll
    for (int j = 0; j < 8; ++j) {
        float4 v;
        v.x = oa[4 * j + 0] * inva; v.y = oa[4 * j + 1] * inva;
        v.z = oa[4 * j + 2] * inva; v.w = oa[4 * j + 3] * inva;
        *(float4*)(opa + 4 * j) = v;
        float4 w;
        w.x = obv[4 * j + 0] * invb; w.y = obv[4 * j + 1] * invb;
        w.z = obv[4 * j + 2] * invb; w.w = obv[4 * j + 3] * invb;
        *(float4*)(opa + 256 * E_DIM + 4 * j) = w;
    }
}

// ---------------------------------------------------------------------------
// K5: out projection + transpose store: out[b][f][l] =
//     sum_e o[b][l][e]*Wout[f][e] + bo[f]
// grid (L/64, E/64, B), block (16,16)
// ---------------------------------------------------------------------------
__global__ __launch_bounds__(256) void k_outproj(const float* __restrict__ ob,
                                                 const float* __restrict__ W,
                                                 const float* __restrict__ bias,
                                                 float* __restrict__ out) {
    const int b  = blockIdx.z;
    const int l0 = blockIdx.x * 64;
    const int f0 = blockIdx.y * 64;
    const int tx = threadIdx.x, ty = threadIdx.y;
    const int lid = ty * 16 + tx;
    __shared__ float As[16][68];
    __shared__ float Ws[16][68];
    float c[4][4] = {};
    const float* sb = ob + (size_t)b * L_SEQ * E_DIM;
    for (int e0 = 0; e0 < E_DIM; e0 += 16) {
        {   // transpose-load o[l][e] -> As[e][l]
            int ll = lid >> 2;
            int e4 = (lid & 3) * 4;
            float4 a = *(const float4*)(sb + (size_t)(l0 + ll) * E_DIM + e0 + e4);
            As[e4 + 0][ll] = a.x; As[e4 + 1][ll] = a.y;
            As[e4 + 2][ll] = a.z; As[e4 + 3][ll] = a.w;
        }
        {
            int f  = lid >> 2;
            int e4 = (lid & 3) * 4;
            float4 w = *(const float4*)(W + (size_t)(f0 + f) * E_DIM + e0 + e4);
            Ws[e4 + 0][f] = w.x; Ws[e4 + 1][f] = w.y;
            Ws[e4 + 2][f] = w.z; Ws[e4 + 3][f] = w.w;
        }
        __syncthreads();
#pragma unroll
        for (int e = 0; e < 16; ++e) {
            float4 a = *(const float4*)&As[e][tx * 4];   // along l
            float4 w = *(const float4*)&Ws[e][ty * 4];   // along f
            float av[4] = {a.x, a.y, a.z, a.w};
            float wv[4] = {w.x, w.y, w.z, w.w};
#pragma unroll
            for (int i = 0; i < 4; ++i)
#pragma unroll
                for (int j = 0; j < 4; ++j) c[i][j] += wv[i] * av[j];
        }
        __syncthreads();
    }
#pragma unroll
    for (int i = 0; i < 4; ++i) {
        const int f = f0 + ty * 4 + i;
        const float bv = bias[f];
        float4 o;
        o.x = c[i][0] + bv; o.y = c[i][1] + bv;
        o.z = c[i][2] + bv; o.w = c[i][3] + bv;
        *(float4*)(out + ((size_t)b * E_DIM + f) * L_SEQ + l0 + tx * 4) = o;
    }
}

// ---------------------------------------------------------------------------
extern "C" void kernel_launch(void* const* d_in, const int* in_sizes, int n_in,
                              void* d_out, int out_size, void* d_ws, size_t ws_size,
                              hipStream_t stream) {
    const float* query = (const float*)d_in[0];
    const float* keys  = (const float*)d_in[1];
    const float* vals  = (const float*)d_in[2];
    const int*   rind  = (const int*)d_in[3];
    const float* ipw   = (const float*)d_in[4];
    const float* ipb   = (const float*)d_in[5];
    const float* opw   = (const float*)d_in[6];
    const float* opb   = (const float*)d_in[7];
    float* out = (float*)d_out;

    char* ws = (char*)d_ws;
    float*  qs_pack = (float*)(ws + 0);                       //  2 MiB
    double* minpart = (double*)(ws + (size_t)2  * 1024 * 1024); // 1 MiB
    int*    sel     = (int*)   (ws + (size_t)3  * 1024 * 1024); // 8 KiB
    float*  kh      = (float*) (ws + (size_t)4  * 1024 * 1024); // 2 MiB
    float*  vh      = (float*) (ws + (size_t)6  * 1024 * 1024); // 2 MiB
    float*  qh      = (float*) (ws + (size_t)8  * 1024 * 1024); // 32 MiB
    float*  obuf    = (float*) (ws + (size_t)40 * 1024 * 1024); // 32 MiB

    const float scale = 0.17677669529663687f;  // 32^-0.5

    k_gather<<<dim3((B_SZ * E_DIM * S_TOP) / 256), 256, 0, stream>>>(query, rind, qs_pack);
    k_dist<<<dim3(L_SEQ / 64, NSPLIT, B_SZ), dim3(16, 16), 0, stream>>>(keys, qs_pack, minpart);
    k_rank<<<dim3(L_SEQ / 256, B_SZ), 256, 0, stream>>>(minpart, sel);
    k_kvproj<<<dim3(E_DIM / 64, S_TOP / 64, B_SZ), dim3(16, 16), 0, stream>>>(
        keys, sel, ipw + (size_t)E_DIM * E_DIM, ipb + E_DIM, kh);
    k_kvproj<<<dim3(E_DIM / 64, S_TOP / 64, B_SZ), dim3(16, 16), 0, stream>>>(
        vals, sel, ipw + (size_t)2 * E_DIM * E_DIM, ipb + 2 * E_DIM, vh);
    k_qproj<<<dim3(E_DIM / 64, L_SEQ / 64, B_SZ), dim3(16, 16), 0, stream>>>(
        query, ipw, ipb, qh, scale);
    k_attn<<<dim3(L_SEQ / 512, NHEAD, B_SZ), 256, 0, stream>>>(qh, kh, vh, obuf);
    k_outproj<<<dim3(L_SEQ / 64, E_DIM / 64, B_SZ), dim3(16, 16), 0, stream>>>(
        obuf, opw, opb, out);
}

// Round 4
// 679.711 us; speedup vs baseline: 1.6545x; 1.2189x over previous
//
#include <hip/hip_runtime.h>
#include <math.h>

#define B_SZ   8
#define E_DIM  256
#define L_SEQ  4096
#define S_TOP  256
#define NHEAD  8
#define HD     32
#define NSPLIT 4   // s-blocks in distance kernel (S_TOP/64)

typedef __attribute__((ext_vector_type(8))) short bf16x8;   // MFMA A/B frag
typedef __attribute__((ext_vector_type(4))) float f32x4;    // MFMA C/D frag

// round-to-nearest-even fp32 -> bf16 (values finite here)
__device__ inline short f2bf(float x) {
    union { float f; unsigned u; } v; v.f = x;
    unsigned r = (v.u + 0x7fff + ((v.u >> 16) & 1)) >> 16;
    return (short)r;
}

// ---------------------------------------------------------------------------
// K0: gather query subset  qs_pack[b][e][s] = query[b][e][ind[b][s]]
// ---------------------------------------------------------------------------
__global__ __launch_bounds__(256) void k_gather(const float* __restrict__ query,
                                                const int* __restrict__ ind,
                                                float* __restrict__ qs_pack) {
    int t = blockIdx.x * 256 + threadIdx.x;     // over B*E*S = 524288
    int s = t & (S_TOP - 1);
    int e = (t >> 8) & (E_DIM - 1);
    int b = t >> 16;
    int idx = ind[b * S_TOP + s];
    qs_pack[t] = query[((size_t)b * E_DIM + e) * L_SEQ + idx];
}

// ---------------------------------------------------------------------------
// K1: tiled LDS L1-distance + min (round-3 structure, unchanged — selection
// numerics must stay bit-identical: fp32 sum over 32-e chunks ascending,
// chunks folded into f64 ascending, exact f64 min).
// grid (L/64, S/64, B), block (16,16), 4x4 micro-tile per thread.
// ---------------------------------------------------------------------------
__global__ __launch_bounds__(256) void k_dist(const float* __restrict__ keys,
                                              const float* __restrict__ qs_pack,
                                              double* __restrict__ minpart) {
    const int b  = blockIdx.z;
    const int ss = blockIdx.y;                  // s-slice [ss*64, ss*64+64)
    const int l0 = blockIdx.x * 64;
    const int tx = threadIdx.x, ty = threadIdx.y;
    const int lid = ty * 16 + tx;
    __shared__ float Ks[16][68];                // [e][l]
    __shared__ float Qs[16][68];                // [e][s]
    __shared__ double red[64][17];              // final cross-ty min
    const float* kb = keys + (size_t)b * E_DIM * L_SEQ;
    const float* qb = qs_pack + (size_t)b * E_DIM * S_TOP + ss * 64;

    float  c[4][4];                             // fp32 sum within 32-e chunk
    double d[4][4];                             // exact f64 chunk accumulator
#pragma unroll
    for (int i = 0; i < 4; ++i)
#pragma unroll
        for (int j = 0; j < 4; ++j) d[i][j] = 0.0;

    for (int e0 = 0; e0 < E_DIM; e0 += 16) {
        __syncthreads();
        {   // stage Ks[e][l]: coalesced float4 along l
            int e  = lid >> 4;
            int l4 = (lid & 15) * 4;
            *(float4*)&Ks[e][l4] = *(const float4*)(kb + (size_t)(e0 + e) * L_SEQ + l0 + l4);
            *(float4*)&Qs[e][l4] = *(const float4*)(qb + (size_t)(e0 + e) * S_TOP + l4);
        }
        __syncthreads();
        if ((e0 & 16) == 0) {
#pragma unroll
            for (int i = 0; i < 4; ++i)
#pragma unroll
                for (int j = 0; j < 4; ++j) c[i][j] = 0.f;
        }
#pragma unroll
        for (int e = 0; e < 16; ++e) {
            float4 kv = *(const float4*)&Ks[e][tx * 4];
            float4 qv = *(const float4*)&Qs[e][ty * 4];
            float kvv[4] = {kv.x, kv.y, kv.z, kv.w};
            float qvv[4] = {qv.x, qv.y, qv.z, qv.w};
#pragma unroll
            for (int i = 0; i < 4; ++i)
#pragma unroll
                for (int j = 0; j < 4; ++j) c[i][j] += fabsf(qvv[i] - kvv[j]);
        }
        if ((e0 & 16) == 16) {                  // fold completed 32-e chunk
#pragma unroll
            for (int i = 0; i < 4; ++i)
#pragma unroll
                for (int j = 0; j < 4; ++j) d[i][j] += (double)c[i][j];
        }
    }
    double dmin[4];
#pragma unroll
    for (int j = 0; j < 4; ++j) {
        double m = d[0][j];
        m = fmin(m, d[1][j]); m = fmin(m, d[2][j]); m = fmin(m, d[3][j]);
        dmin[j] = m;
    }
    __syncthreads();
#pragma unroll
    for (int j = 0; j < 4; ++j) red[tx * 4 + j][ty] = dmin[j];
    __syncthreads();
    if (lid < 64) {
        double m = red[lid][0];
#pragma unroll
        for (int t = 1; t < 16; ++t) m = fmin(m, red[lid][t]);
        minpart[((size_t)(b * NSPLIT + ss)) * L_SEQ + l0 + lid] = m;
    }
}

// ---------------------------------------------------------------------------
// K2: combine split-mins, rank each token, emit selected indices (rank<256).
// Exact f64 compares with index tie-break == lax.top_k stable semantics.
// ---------------------------------------------------------------------------
__global__ __launch_bounds__(256) void k_rank(const double* __restrict__ minpart,
                                              int* __restrict__ sel) {
    const int b = blockIdx.y;
    const int l = blockIdx.x * 256 + threadIdx.x;
    __shared__ double sd[L_SEQ];                // 32 KiB
    const double* mp = minpart + (size_t)b * NSPLIT * L_SEQ;
    for (int j = threadIdx.x; j < L_SEQ; j += 256) {
        double v = mp[j];
        v = fmin(v, mp[L_SEQ + j]);
        v = fmin(v, mp[2 * L_SEQ + j]);
        v = fmin(v, mp[3 * L_SEQ + j]);
        sd[j] = v;
    }
    __syncthreads();
    const double dl = sd[l];
    int rank = 0;
#pragma unroll 4
    for (int j = 0; j < L_SEQ; ++j) {
        double dj = sd[j];
        rank += (dj < dl) || (dj == dl && j < l) ? 1 : 0;
    }
    if (rank < S_TOP) sel[b * S_TOP + rank] = l;
}

// ---------------------------------------------------------------------------
// K3: gather + project selected keys/values -> bf16 outputs for MFMA attn.
// TR=0 (keys):   dst[b][k][f] bf16
// TR=1 (values): dst[b][f][k] bf16 (transposed so PV B-frags are contiguous)
// grid (E/64, S_TOP/64, B), block (16,16), 4x4 micro-tile
// ---------------------------------------------------------------------------
template <int TR>
__global__ __launch_bounds__(256) void k_kvproj(const float* __restrict__ src,
                                                const int* __restrict__ sel,
                                                const float* __restrict__ W,
                                                const float* __restrict__ bias,
                                                short* __restrict__ dst) {
    const int b  = blockIdx.z;
    const int f0 = blockIdx.x * 64;
    const int k0 = blockIdx.y * 64;
    const int tx = threadIdx.x, ty = threadIdx.y;
    const int lid = ty * 16 + tx;
    __shared__ float As[16][68];
    __shared__ float Ws[16][68];
    float c[4][4] = {};
    const float* sb = src + (size_t)b * E_DIM * L_SEQ;
    const int* selb = sel + b * S_TOP;
    for (int e0 = 0; e0 < E_DIM; e0 += 16) {
        {   // As[e][k] gather (scattered loads)
            int e  = lid >> 4;
            int k4 = (lid & 15) * 4;
#pragma unroll
            for (int c2 = 0; c2 < 4; ++c2) {
                int kk = k4 + c2;
                As[e][kk] = sb[(size_t)(e0 + e) * L_SEQ + selb[k0 + kk]];
            }
        }
        {   // Ws[e][f] from row-major W[f][e]
            int f  = lid >> 2;
            int e4 = (lid & 3) * 4;
            float4 w = *(const float4*)(W + (size_t)(f0 + f) * E_DIM + e0 + e4);
            Ws[e4 + 0][f] = w.x; Ws[e4 + 1][f] = w.y;
            Ws[e4 + 2][f] = w.z; Ws[e4 + 3][f] = w.w;
        }
        __syncthreads();
#pragma unroll
        for (int e = 0; e < 16; ++e) {
            float4 a = *(const float4*)&As[e][ty * 4];
            float4 w = *(const float4*)&Ws[e][tx * 4];
            float av[4] = {a.x, a.y, a.z, a.w};
            float wv[4] = {w.x, w.y, w.z, w.w};
#pragma unroll
            for (int i = 0; i < 4; ++i)
#pragma unroll
                for (int j = 0; j < 4; ++j) c[i][j] += av[i] * wv[j];
        }
        __syncthreads();
    }
    if (TR == 0) {
#pragma unroll
        for (int i = 0; i < 4; ++i) {
            short4 o;
            o.x = f2bf(c[i][0] + bias[f0 + tx * 4 + 0]);
            o.y = f2bf(c[i][1] + bias[f0 + tx * 4 + 1]);
            o.z = f2bf(c[i][2] + bias[f0 + tx * 4 + 2]);
            o.w = f2bf(c[i][3] + bias[f0 + tx * 4 + 3]);
            *(short4*)(dst + ((size_t)b * S_TOP + k0 + ty * 4 + i) * E_DIM + f0 + tx * 4) = o;
        }
    } else {
#pragma unroll
        for (int j = 0; j < 4; ++j) {
            const float bv = bias[f0 + tx * 4 + j];
            short4 o;
            o.x = f2bf(c[0][j] + bv); o.y = f2bf(c[1][j] + bv);
            o.z = f2bf(c[2][j] + bv); o.w = f2bf(c[3][j] + bv);
            *(short4*)(dst + ((size_t)b * E_DIM + f0 + tx * 4 + j) * S_TOP + k0 + ty * 4) = o;
        }
    }
}

// ---------------------------------------------------------------------------
// K3q: Q projection -> bf16 [b][l][f], scale folded in.
// grid (E/64, L/64, B), block (16,16)
// ---------------------------------------------------------------------------
__global__ __launch_bounds__(256) void k_qproj(const float* __restrict__ query,
                                               const float* __restrict__ W,
                                               const float* __restrict__ bias,
                                               short* __restrict__ qhb,
                                               float scale) {
    const int b  = blockIdx.z;
    const int f0 = blockIdx.x * 64;
    const int l0 = blockIdx.y * 64;
    const int tx = threadIdx.x, ty = threadIdx.y;
    const int lid = ty * 16 + tx;
    __shared__ float As[16][68];
    __shared__ float Ws[16][68];
    float c[4][4] = {};
    const float* sb = query + (size_t)b * E_DIM * L_SEQ;
    for (int e0 = 0; e0 < E_DIM; e0 += 16) {
        {
            int e  = lid >> 4;
            int l4 = (lid & 15) * 4;
            *(float4*)&As[e][l4] = *(const float4*)(sb + (size_t)(e0 + e) * L_SEQ + l0 + l4);
        }
        {
            int f  = lid >> 2;
            int e4 = (lid & 3) * 4;
            float4 w = *(const float4*)(W + (size_t)(f0 + f) * E_DIM + e0 + e4);
            Ws[e4 + 0][f] = w.x; Ws[e4 + 1][f] = w.y;
            Ws[e4 + 2][f] = w.z; Ws[e4 + 3][f] = w.w;
        }
        __syncthreads();
#pragma unroll
        for (int e = 0; e < 16; ++e) {
            float4 a = *(const float4*)&As[e][ty * 4];
            float4 w = *(const float4*)&Ws[e][tx * 4];
            float av[4] = {a.x, a.y, a.z, a.w};
            float wv[4] = {w.x, w.y, w.z, w.w};
#pragma unroll
            for (int i = 0; i < 4; ++i)
#pragma unroll
                for (int j = 0; j < 4; ++j) c[i][j] += av[i] * wv[j];
        }
        __syncthreads();
    }
#pragma unroll
    for (int i = 0; i < 4; ++i) {
        short4 o;
        o.x = f2bf(scale * (c[i][0] + bias[f0 + tx * 4 + 0]));
        o.y = f2bf(scale * (c[i][1] + bias[f0 + tx * 4 + 1]));
        o.z = f2bf(scale * (c[i][2] + bias[f0 + tx * 4 + 2]));
        o.w = f2bf(scale * (c[i][3] + bias[f0 + tx * 4 + 3]));
        *(short4*)(qhb + ((size_t)b * L_SEQ + l0 + ty * 4 + i) * E_DIM + f0 + tx * 4) = o;
    }
}

// ---------------------------------------------------------------------------
// K4 (round-4 rewrite): bf16 MFMA flash attention.
// Per wave: 16-query tile. S[16x256] via 16x mfma_16x16x32 (K-dim = HD = 32),
// register softmax (shfl_xor row reduces), P -> LDS (bf16, stride 264 breaks
// the 528B power-of-2 bank stride) -> A-frags for PV, 16x mfma.
// A-frag: A[m=lane&15][k=quad*8+j]; B-frag: B[k=quad*8+j][n=lane&15];
// C/D: row=quad*4+reg, col=lane&15  (m89/m91/m120-verified layouts).
// No __syncthreads: P regions are wave-private.
// grid (L/64, H, B), block 256 (4 waves).
// ---------------------------------------------------------------------------
__global__ __launch_bounds__(256) void k_attn(const short* __restrict__ qhb,
                                              const short* __restrict__ khb,
                                              const short* __restrict__ vtb,
                                              float* __restrict__ ob) {
    __shared__ short P[4][16][264];             // 33 KB, wave-private slices
    const int b = blockIdx.z, h = blockIdx.y;
    const int wv   = threadIdx.x >> 6;
    const int lane = threadIdx.x & 63;
    const int quad = lane >> 4;
    const int m    = lane & 15;
    const int l0 = blockIdx.x * 64 + wv * 16;

    // Q A-frag: Q[l0+m][h*32 + quad*8 + j]
    const short* qp = qhb + ((size_t)b * L_SEQ + l0 + m) * E_DIM + h * HD + quad * 8;
    const bf16x8 qa = *(const bf16x8*)qp;

    // S = Q K^T: one MFMA per 16-key tile
    const short* kb = khb + (size_t)b * S_TOP * E_DIM + h * HD + quad * 8;
    f32x4 sacc[16];
    const f32x4 zero = {0.f, 0.f, 0.f, 0.f};
#pragma unroll
    for (int t = 0; t < 16; ++t) {
        bf16x8 kf = *(const bf16x8*)(kb + (size_t)(t * 16 + m) * E_DIM);
        sacc[t] = __builtin_amdgcn_mfma_f32_16x16x32_bf16(qa, kf, zero, 0, 0, 0);
    }

    // row max over 256 keys (16 in-thread tiles x 16 lanes)
    float mx[4], ssum[4];
#pragma unroll
    for (int r = 0; r < 4; ++r) {
        float v = sacc[0][r];
#pragma unroll
        for (int t = 1; t < 16; ++t) v = fmaxf(v, sacc[t][r]);
#pragma unroll
        for (int off = 1; off < 16; off <<= 1) v = fmaxf(v, __shfl_xor(v, off, 16));
        mx[r] = v;
        ssum[r] = 0.f;
    }
    // P = exp(S - mx): accumulate fp32 row sums, store bf16 to LDS
#pragma unroll
    for (int t = 0; t < 16; ++t) {
#pragma unroll
        for (int r = 0; r < 4; ++r) {
            float p = __expf(sacc[t][r] - mx[r]);
            ssum[r] += p;
            P[wv][quad * 4 + r][t * 16 + m] = f2bf(p);
        }
    }
#pragma unroll
    for (int r = 0; r < 4; ++r) {
        float v = ssum[r];
#pragma unroll
        for (int off = 1; off < 16; off <<= 1) v += __shfl_xor(v, off, 16);
        ssum[r] = v;
    }

    // O = P V: A from LDS (wave-private, compiler inserts lgkm waits),
    // B from transposed V [d][key] (contiguous 16B per lane)
    const short* vb = vtb + ((size_t)b * E_DIM + h * HD) * S_TOP;
    f32x4 oacc[2];
#pragma unroll
    for (int dt = 0; dt < 2; ++dt) {
        f32x4 acc = zero;
#pragma unroll
        for (int k0 = 0; k0 < S_TOP; k0 += 32) {
            bf16x8 pa = *(const bf16x8*)&P[wv][m][k0 + quad * 8];
            bf16x8 vf = *(const bf16x8*)(vb + (size_t)(dt * 16 + m) * S_TOP + k0 + quad * 8);
            acc = __builtin_amdgcn_mfma_f32_16x16x32_bf16(pa, vf, acc, 0, 0, 0);
        }
        oacc[dt] = acc;
    }

    float* op = ob + ((size_t)b * L_SEQ + l0) * E_DIM + h * HD;
#pragma unroll
    for (int r = 0; r < 4; ++r) {
        const float inv = 1.0f / ssum[r];
#pragma unroll
        for (int dt = 0; dt < 2; ++dt)
            op[(size_t)(quad * 4 + r) * E_DIM + dt * 16 + m] = oacc[dt][r] * inv;
    }
}

// ---------------------------------------------------------------------------
// K5: out projection + transpose store: out[b][f][l] =
//     sum_e o[b][l][e]*Wout[f][e] + bo[f]
// grid (L/64, E/64, B), block (16,16)
// ---------------------------------------------------------------------------
__global__ __launch_bounds__(256) void k_outproj(const float* __restrict__ ob,
                                                 const float* __restrict__ W,
                                                 const float* __restrict__ bias,
                                                 float* __restrict__ out) {
    const int b  = blockIdx.z;
    const int l0 = blockIdx.x * 64;
    const int f0 = blockIdx.y * 64;
    const int tx = threadIdx.x, ty = threadIdx.y;
    const int lid = ty * 16 + tx;
    __shared__ float As[16][68];
    __shared__ float Ws[16][68];
    float c[4][4] = {};
    const float* sb = ob + (size_t)b * L_SEQ * E_DIM;
    for (int e0 = 0; e0 < E_DIM; e0 += 16) {
        {   // transpose-load o[l][e] -> As[e][l]
            int ll = lid >> 2;
            int e4 = (lid & 3) * 4;
            float4 a = *(const float4*)(sb + (size_t)(l0 + ll) * E_DIM + e0 + e4);
            As[e4 + 0][ll] = a.x; As[e4 + 1][ll] = a.y;
            As[e4 + 2][ll] = a.z; As[e4 + 3][ll] = a.w;
        }
        {
            int f  = lid >> 2;
            int e4 = (lid & 3) * 4;
            float4 w = *(const float4*)(W + (size_t)(f0 + f) * E_DIM + e0 + e4);
            Ws[e4 + 0][f] = w.x; Ws[e4 + 1][f] = w.y;
            Ws[e4 + 2][f] = w.z; Ws[e4 + 3][f] = w.w;
        }
        __syncthreads();
#pragma unroll
        for (int e = 0; e < 16; ++e) {
            float4 a = *(const float4*)&As[e][tx * 4];   // along l
            float4 w = *(const float4*)&Ws[e][ty * 4];   // along f
            float av[4] = {a.x, a.y, a.z, a.w};
            float wv[4] = {w.x, w.y, w.z, w.w};
#pragma unroll
            for (int i = 0; i < 4; ++i)
#pragma unroll
                for (int j = 0; j < 4; ++j) c[i][j] += wv[i] * av[j];
        }
        __syncthreads();
    }
#pragma unroll
    for (int i = 0; i < 4; ++i) {
        const int f = f0 + ty * 4 + i;
        const float bv = bias[f];
        float4 o;
        o.x = c[i][0] + bv; o.y = c[i][1] + bv;
        o.z = c[i][2] + bv; o.w = c[i][3] + bv;
        *(float4*)(out + ((size_t)b * E_DIM + f) * L_SEQ + l0 + tx * 4) = o;
    }
}

// ---------------------------------------------------------------------------
extern "C" void kernel_launch(void* const* d_in, const int* in_sizes, int n_in,
                              void* d_out, int out_size, void* d_ws, size_t ws_size,
                              hipStream_t stream) {
    const float* query = (const float*)d_in[0];
    const float* keys  = (const float*)d_in[1];
    const float* vals  = (const float*)d_in[2];
    const int*   rind  = (const int*)d_in[3];
    const float* ipw   = (const float*)d_in[4];
    const float* ipb   = (const float*)d_in[5];
    const float* opw   = (const float*)d_in[6];
    const float* opb   = (const float*)d_in[7];
    float* out = (float*)d_out;

    char* ws = (char*)d_ws;
    float*  qs_pack = (float*)(ws + 0);                         //  2 MiB
    double* minpart = (double*)(ws + (size_t)2  * 1024 * 1024); //  1 MiB
    int*    sel     = (int*)   (ws + (size_t)3  * 1024 * 1024); //  8 KiB
    short*  khb     = (short*) (ws + (size_t)4  * 1024 * 1024); //  1 MiB bf16
    short*  vtb     = (short*) (ws + (size_t)6  * 1024 * 1024); //  1 MiB bf16
    short*  qhb     = (short*) (ws + (size_t)8  * 1024 * 1024); // 16 MiB bf16
    float*  obuf    = (float*) (ws + (size_t)40 * 1024 * 1024); // 32 MiB

    const float scale = 0.17677669529663687f;  // 32^-0.5

    k_gather<<<dim3((B_SZ * E_DIM * S_TOP) / 256), 256, 0, stream>>>(query, rind, qs_pack);
    k_dist<<<dim3(L_SEQ / 64, NSPLIT, B_SZ), dim3(16, 16), 0, stream>>>(keys, qs_pack, minpart);
    k_rank<<<dim3(L_SEQ / 256, B_SZ), 256, 0, stream>>>(minpart, sel);
    k_kvproj<0><<<dim3(E_DIM / 64, S_TOP / 64, B_SZ), dim3(16, 16), 0, stream>>>(
        keys, sel, ipw + (size_t)E_DIM * E_DIM, ipb + E_DIM, khb);
    k_kvproj<1><<<dim3(E_DIM / 64, S_TOP / 64, B_SZ), dim3(16, 16), 0, stream>>>(
        vals, sel, ipw + (size_t)2 * E_DIM * E_DIM, ipb + 2 * E_DIM, vtb);
    k_qproj<<<dim3(E_DIM / 64, L_SEQ / 64, B_SZ), dim3(16, 16), 0, stream>>>(
        query, ipw, ipb, qhb, scale);
    k_attn<<<dim3(L_SEQ / 64, NHEAD, B_SZ), 256, 0, stream>>>(qhb, khb, vtb, obuf);
    k_outproj<<<dim3(L_SEQ / 64, E_DIM / 64, B_SZ), dim3(16, 16), 0, stream>>>(
        obuf, opw, opb, out);
}

// Round 5
// 632.650 us; speedup vs baseline: 1.7776x; 1.0744x over previous
//
#include <hip/hip_runtime.h>
#include <math.h>

#define B_SZ   8
#define E_DIM  256
#define L_SEQ  4096
#define S_TOP  256
#define NHEAD  8
#define HD     32
#define NSPLIT 4   // s-blocks in distance kernel (S_TOP/64)

typedef __attribute__((ext_vector_type(8))) short bf16x8;   // MFMA A/B frag
typedef __attribute__((ext_vector_type(4))) float f32x4;    // MFMA C/D frag

// round-to-nearest-even fp32 -> bf16 (values finite here)
__device__ inline short f2bf(float x) {
    union { float f; unsigned u; } v; v.f = x;
    unsigned r = (v.u + 0x7fff + ((v.u >> 16) & 1)) >> 16;
    return (short)r;
}

// ---------------------------------------------------------------------------
// K0: gather query subset, TRANSPOSED layout: qs_pack[b][s][e]
// (round-5: k_dist now wants Q rows contiguous in e for b128 broadcasts)
// ---------------------------------------------------------------------------
__global__ __launch_bounds__(256) void k_gather(const float* __restrict__ query,
                                                const int* __restrict__ ind,
                                                float* __restrict__ qs_pack) {
    int t = blockIdx.x * 256 + threadIdx.x;     // over B*S*E = 524288
    int e = t & (E_DIM - 1);
    int s = (t >> 8) & (S_TOP - 1);
    int b = t >> 16;
    int idx = ind[b * S_TOP + s];
    qs_pack[t] = query[((size_t)b * E_DIM + e) * L_SEQ + idx];
}

// ---------------------------------------------------------------------------
// K1 (round-5 rewrite): keys-in-registers L1-distance + min.
// Round-4 was at the LDS-port roofline (32 LDS-B per 32 VALU-ops/thread =
// 128 B/cyc/CU demand). Now: per 32-e chunk, each thread holds kr[32] in
// VGPRs (read once, reused over 16 s); Q rows are wave-broadcast b128 reads
// (all 64 lanes same address -> no port pressure).
// Numerics bit-identical to rounds 3/4: per (l,s), fp32 sum over the same
// ascending 32-e chunks, each chunk folded into f64 ascending, exact f64 min.
// grid (L/64, NSPLIT, B), block (64,4): lane=l, ty=16-s group.
// ---------------------------------------------------------------------------
__global__ __launch_bounds__(256) void k_dist(const float* __restrict__ keys,
                                              const float* __restrict__ qs_pack,
                                              double* __restrict__ minpart) {
    const int b    = blockIdx.z;
    const int ss   = blockIdx.y;                // s-slice [ss*64, ss*64+64)
    const int l0   = blockIdx.x * 64;
    const int lane = threadIdx.x;               // 0..63 : l
    const int sg   = threadIdx.y;               // 0..3  : s-group of 16
    const int lid  = sg * 64 + lane;
    __shared__ float  Ks[32][64];               // [e][l]  8 KiB
    __shared__ float  Qs[64][36];               // [s][e]  9 KiB (144B rows, 16B-aligned)
    __shared__ double red[4][64];               // cross-sg min, 2 KiB
    const float* kb = keys + (size_t)b * E_DIM * L_SEQ + l0;
    const float* qb = qs_pack + ((size_t)b * S_TOP + ss * 64) * E_DIM;

    double d[16];
#pragma unroll
    for (int j = 0; j < 16; ++j) d[j] = 0.0;

    for (int c0 = 0; c0 < E_DIM; c0 += 32) {
        __syncthreads();
#pragma unroll
        for (int r = 0; r < 2; ++r) {           // stage 512+512 float4
            int f4 = lid + 256 * r;
            int e  = f4 >> 4, l4 = (f4 & 15) * 4;
            *(float4*)&Ks[e][l4] = *(const float4*)(kb + (size_t)(c0 + e) * L_SEQ + l4);
            int s  = f4 >> 3, e4 = (f4 & 7) * 4;
            *(float4*)&Qs[s][e4] = *(const float4*)(qb + (size_t)s * E_DIM + c0 + e4);
        }
        __syncthreads();
        float kr[32];
#pragma unroll
        for (int e = 0; e < 32; ++e) kr[e] = Ks[e][lane];   // 2-way, free
#pragma unroll
        for (int si = 0; si < 16; ++si) {
            const float* qrow = &Qs[sg * 16 + si][0];       // wave-broadcast
            float csum = 0.f;
#pragma unroll
            for (int e = 0; e < 32; ++e) csum += fabsf(kr[e] - qrow[e]);
            d[si] += (double)csum;
        }
    }
    double md = d[0];
#pragma unroll
    for (int j = 1; j < 16; ++j) md = fmin(md, d[j]);
    red[sg][lane] = md;
    __syncthreads();
    if (sg == 0) {
        double m = red[0][lane];
        m = fmin(m, red[1][lane]);
        m = fmin(m, red[2][lane]);
        m = fmin(m, red[3][lane]);
        minpart[((size_t)(b * NSPLIT + ss)) * L_SEQ + l0 + lane] = m;
    }
}

// ---------------------------------------------------------------------------
// K2: combine split-mins, rank each token, emit selected indices (rank<256).
// Exact f64 compares with index tie-break == lax.top_k stable semantics.
// ---------------------------------------------------------------------------
__global__ __launch_bounds__(256) void k_rank(const double* __restrict__ minpart,
                                              int* __restrict__ sel) {
    const int b = blockIdx.y;
    const int l = blockIdx.x * 256 + threadIdx.x;
    __shared__ double sd[L_SEQ];                // 32 KiB
    const double* mp = minpart + (size_t)b * NSPLIT * L_SEQ;
    for (int j = threadIdx.x; j < L_SEQ; j += 256) {
        double v = mp[j];
        v = fmin(v, mp[L_SEQ + j]);
        v = fmin(v, mp[2 * L_SEQ + j]);
        v = fmin(v, mp[3 * L_SEQ + j]);
        sd[j] = v;
    }
    __syncthreads();
    const double dl = sd[l];
    int rank = 0;
#pragma unroll 4
    for (int j = 0; j < L_SEQ; ++j) {
        double dj = sd[j];
        rank += (dj < dl) || (dj == dl && j < l) ? 1 : 0;
    }
    if (rank < S_TOP) sel[b * S_TOP + rank] = l;
}

// ---------------------------------------------------------------------------
// K3: gather + project selected keys/values -> bf16 outputs for MFMA attn.
// TR=0 (keys):   dst[b][k][f] bf16
// TR=1 (values): dst[b][f][k] bf16 (transposed so PV B-frags are contiguous)
// grid (E/64, S_TOP/64, B), block (16,16), 4x4 micro-tile
// ---------------------------------------------------------------------------
template <int TR>
__global__ __launch_bounds__(256) void k_kvproj(const float* __restrict__ src,
                                                const int* __restrict__ sel,
                                                const float* __restrict__ W,
                                                const float* __restrict__ bias,
                                                short* __restrict__ dst) {
    const int b  = blockIdx.z;
    const int f0 = blockIdx.x * 64;
    const int k0 = blockIdx.y * 64;
    const int tx = threadIdx.x, ty = threadIdx.y;
    const int lid = ty * 16 + tx;
    __shared__ float As[16][68];
    __shared__ float Ws[16][68];
    float c[4][4] = {};
    const float* sb = src + (size_t)b * E_DIM * L_SEQ;
    const int* selb = sel + b * S_TOP;
    for (int e0 = 0; e0 < E_DIM; e0 += 16) {
        {   // As[e][k] gather (scattered loads)
            int e  = lid >> 4;
            int k4 = (lid & 15) * 4;
#pragma unroll
            for (int c2 = 0; c2 < 4; ++c2) {
                int kk = k4 + c2;
                As[e][kk] = sb[(size_t)(e0 + e) * L_SEQ + selb[k0 + kk]];
            }
        }
        {   // Ws[e][f] from row-major W[f][e]
            int f  = lid >> 2;
            int e4 = (lid & 3) * 4;
            float4 w = *(const float4*)(W + (size_t)(f0 + f) * E_DIM + e0 + e4);
            Ws[e4 + 0][f] = w.x; Ws[e4 + 1][f] = w.y;
            Ws[e4 + 2][f] = w.z; Ws[e4 + 3][f] = w.w;
        }
        __syncthreads();
#pragma unroll
        for (int e = 0; e < 16; ++e) {
            float4 a = *(const float4*)&As[e][ty * 4];
            float4 w = *(const float4*)&Ws[e][tx * 4];
            float av[4] = {a.x, a.y, a.z, a.w};
            float wv[4] = {w.x, w.y, w.z, w.w};
#pragma unroll
            for (int i = 0; i < 4; ++i)
#pragma unroll
                for (int j = 0; j < 4; ++j) c[i][j] += av[i] * wv[j];
        }
        __syncthreads();
    }
    if (TR == 0) {
#pragma unroll
        for (int i = 0; i < 4; ++i) {
            short4 o;
            o.x = f2bf(c[i][0] + bias[f0 + tx * 4 + 0]);
            o.y = f2bf(c[i][1] + bias[f0 + tx * 4 + 1]);
            o.z = f2bf(c[i][2] + bias[f0 + tx * 4 + 2]);
            o.w = f2bf(c[i][3] + bias[f0 + tx * 4 + 3]);
            *(short4*)(dst + ((size_t)b * S_TOP + k0 + ty * 4 + i) * E_DIM + f0 + tx * 4) = o;
        }
    } else {
#pragma unroll
        for (int j = 0; j < 4; ++j) {
            const float bv = bias[f0 + tx * 4 + j];
            short4 o;
            o.x = f2bf(c[0][j] + bv); o.y = f2bf(c[1][j] + bv);
            o.z = f2bf(c[2][j] + bv); o.w = f2bf(c[3][j] + bv);
            *(short4*)(dst + ((size_t)b * E_DIM + f0 + tx * 4 + j) * S_TOP + k0 + ty * 4) = o;
        }
    }
}

// ---------------------------------------------------------------------------
// K3q (round-5: 128x128 tile, 8x8 micro-tile -> 1 FMA/LDS-byte).
// qh[b][l][f] = bf16(scale*(sum_e query[b][e][l]*Wq[f][e] + bq[f]))
// Accumulation per element: one fmac per e, ascending -> bit-identical.
// grid (E/128, L/128, B), block (16,16)
// ---------------------------------------------------------------------------
__global__ __launch_bounds__(256) void k_qproj(const float* __restrict__ query,
                                               const float* __restrict__ W,
                                               const float* __restrict__ bias,
                                               short* __restrict__ qhb,
                                               float scale) {
    const int b  = blockIdx.z;
    const int f0 = blockIdx.x * 128;
    const int l0 = blockIdx.y * 128;
    const int tx = threadIdx.x, ty = threadIdx.y;
    const int lid = ty * 16 + tx;
    __shared__ float As[8][132];                // [e][l]
    __shared__ float Ws[8][132];                // [e][f]
    float c[8][8] = {};
    const float* sb = query + (size_t)b * E_DIM * L_SEQ + l0;
    for (int e0 = 0; e0 < E_DIM; e0 += 8) {
        __syncthreads();
        {   // A: 8e x 128l, 1 float4/thread, coalesced along l
            int e  = lid >> 5, l4 = (lid & 31) * 4;
            *(float4*)&As[e][l4] = *(const float4*)(sb + (size_t)(e0 + e) * L_SEQ + l4);
            // W: 128f x 8e, transpose-staged
            int f  = lid >> 1, e4 = (lid & 1) * 4;
            float4 w = *(const float4*)(W + (size_t)(f0 + f) * E_DIM + e0 + e4);
            Ws[e4 + 0][f] = w.x; Ws[e4 + 1][f] = w.y;
            Ws[e4 + 2][f] = w.z; Ws[e4 + 3][f] = w.w;
        }
        __syncthreads();
#pragma unroll
        for (int e = 0; e < 8; ++e) {
            float4 a0 = *(const float4*)&As[e][tx * 4];
            float4 a1 = *(const float4*)&As[e][64 + tx * 4];
            float4 w0 = *(const float4*)&Ws[e][ty * 4];
            float4 w1 = *(const float4*)&Ws[e][64 + ty * 4];
            float av[8] = {a0.x, a0.y, a0.z, a0.w, a1.x, a1.y, a1.z, a1.w};
            float wv[8] = {w0.x, w0.y, w0.z, w0.w, w1.x, w1.y, w1.z, w1.w};
#pragma unroll
            for (int i = 0; i < 8; ++i)
#pragma unroll
                for (int j = 0; j < 8; ++j) c[i][j] += av[i] * wv[j];
        }
    }
    float bv[8];
#pragma unroll
    for (int j = 0; j < 8; ++j)
        bv[j] = bias[f0 + ((j < 4) ? ty * 4 + j : 64 + ty * 4 + (j - 4))];
#pragma unroll
    for (int i = 0; i < 8; ++i) {
        const int l = l0 + ((i < 4) ? tx * 4 + i : 64 + tx * 4 + (i - 4));
        short* row = qhb + ((size_t)b * L_SEQ + l) * E_DIM + f0;
        short4 o0, o1;
        o0.x = f2bf(scale * (c[i][0] + bv[0]));
        o0.y = f2bf(scale * (c[i][1] + bv[1]));
        o0.z = f2bf(scale * (c[i][2] + bv[2]));
        o0.w = f2bf(scale * (c[i][3] + bv[3]));
        o1.x = f2bf(scale * (c[i][4] + bv[4]));
        o1.y = f2bf(scale * (c[i][5] + bv[5]));
        o1.z = f2bf(scale * (c[i][6] + bv[6]));
        o1.w = f2bf(scale * (c[i][7] + bv[7]));
        *(short4*)(row + ty * 4) = o0;
        *(short4*)(row + 64 + ty * 4) = o1;
    }
}

// ---------------------------------------------------------------------------
// K4: bf16 MFMA flash attention (round-4 structure, unchanged).
// grid (L/64, H, B), block 256 (4 waves).
// ---------------------------------------------------------------------------
__global__ __launch_bounds__(256) void k_attn(const short* __restrict__ qhb,
                                              const short* __restrict__ khb,
                                              const short* __restrict__ vtb,
                                              float* __restrict__ ob) {
    __shared__ short P[4][16][264];             // 33 KB, wave-private slices
    const int b = blockIdx.z, h = blockIdx.y;
    const int wv   = threadIdx.x >> 6;
    const int lane = threadIdx.x & 63;
    const int quad = lane >> 4;
    const int m    = lane & 15;
    const int l0 = blockIdx.x * 64 + wv * 16;

    const short* qp = qhb + ((size_t)b * L_SEQ + l0 + m) * E_DIM + h * HD + quad * 8;
    const bf16x8 qa = *(const bf16x8*)qp;

    const short* kb = khb + (size_t)b * S_TOP * E_DIM + h * HD + quad * 8;
    f32x4 sacc[16];
    const f32x4 zero = {0.f, 0.f, 0.f, 0.f};
#pragma unroll
    for (int t = 0; t < 16; ++t) {
        bf16x8 kf = *(const bf16x8*)(kb + (size_t)(t * 16 + m) * E_DIM);
        sacc[t] = __builtin_amdgcn_mfma_f32_16x16x32_bf16(qa, kf, zero, 0, 0, 0);
    }

    float mx[4], ssum[4];
#pragma unroll
    for (int r = 0; r < 4; ++r) {
        float v = sacc[0][r];
#pragma unroll
        for (int t = 1; t < 16; ++t) v = fmaxf(v, sacc[t][r]);
#pragma unroll
        for (int off = 1; off < 16; off <<= 1) v = fmaxf(v, __shfl_xor(v, off, 16));
        mx[r] = v;
        ssum[r] = 0.f;
    }
#pragma unroll
    for (int t = 0; t < 16; ++t) {
#pragma unroll
        for (int r = 0; r < 4; ++r) {
            float p = __expf(sacc[t][r] - mx[r]);
            ssum[r] += p;
            P[wv][quad * 4 + r][t * 16 + m] = f2bf(p);
        }
    }
#pragma unroll
    for (int r = 0; r < 4; ++r) {
        float v = ssum[r];
#pragma unroll
        for (int off = 1; off < 16; off <<= 1) v += __shfl_xor(v, off, 16);
        ssum[r] = v;
    }

    const short* vb = vtb + ((size_t)b * E_DIM + h * HD) * S_TOP;
    f32x4 oacc[2];
#pragma unroll
    for (int dt = 0; dt < 2; ++dt) {
        f32x4 acc = zero;
#pragma unroll
        for (int k0 = 0; k0 < S_TOP; k0 += 32) {
            bf16x8 pa = *(const bf16x8*)&P[wv][m][k0 + quad * 8];
            bf16x8 vf = *(const bf16x8*)(vb + (size_t)(dt * 16 + m) * S_TOP + k0 + quad * 8);
            acc = __builtin_amdgcn_mfma_f32_16x16x32_bf16(pa, vf, acc, 0, 0, 0);
        }
        oacc[dt] = acc;
    }

    float* op = ob + ((size_t)b * L_SEQ + l0) * E_DIM + h * HD;
#pragma unroll
    for (int r = 0; r < 4; ++r) {
        const float inv = 1.0f / ssum[r];
#pragma unroll
        for (int dt = 0; dt < 2; ++dt)
            op[(size_t)(quad * 4 + r) * E_DIM + dt * 16 + m] = oacc[dt][r] * inv;
    }
}

// ---------------------------------------------------------------------------
// K5 (round-5: 128x128 tile, 8x8 micro-tile).
// out[b][f][l] = sum_e o[b][l][e]*Wout[f][e] + bo[f]
// c[i][j]: i -> f, j -> l (so stores are float4 along l).
// grid (L/128, E/128, B), block (16,16)
// ---------------------------------------------------------------------------
__global__ __launch_bounds__(256) void k_outproj(const float* __restrict__ ob,
                                                 const float* __restrict__ W,
                                                 const float* __restrict__ bias,
                                                 float* __restrict__ out) {
    const int b  = blockIdx.z;
    const int l0 = blockIdx.x * 128;
    const int f0 = blockIdx.y * 128;
    const int tx = threadIdx.x, ty = threadIdx.y;
    const int lid = ty * 16 + tx;
    __shared__ float As[8][132];                // [e][l]
    __shared__ float Ws[8][132];                // [e][f]
    float c[8][8] = {};
    const float* sb = ob + (size_t)b * L_SEQ * E_DIM;
    for (int e0 = 0; e0 < E_DIM; e0 += 8) {
        __syncthreads();
        {   // A: transpose-stage o[l][e] -> As[e][l]
            int l  = lid >> 1, e4 = (lid & 1) * 4;
            float4 a = *(const float4*)(sb + (size_t)(l0 + l) * E_DIM + e0 + e4);
            As[e4 + 0][l] = a.x; As[e4 + 1][l] = a.y;
            As[e4 + 2][l] = a.z; As[e4 + 3][l] = a.w;
            // W: 128f x 8e, transpose-staged
            int f  = lid >> 1, e4w = (lid & 1) * 4;
            float4 w = *(const float4*)(W + (size_t)(f0 + f) * E_DIM + e0 + e4w);
            Ws[e4w + 0][f] = w.x; Ws[e4w + 1][f] = w.y;
            Ws[e4w + 2][f] = w.z; Ws[e4w + 3][f] = w.w;
        }
        __syncthreads();
#pragma unroll
        for (int e = 0; e < 8; ++e) {
            float4 a0 = *(const float4*)&As[e][tx * 4];
            float4 a1 = *(const float4*)&As[e][64 + tx * 4];
            float4 w0 = *(const float4*)&Ws[e][ty * 4];
            float4 w1 = *(const float4*)&Ws[e][64 + ty * 4];
            float av[8] = {a0.x, a0.y, a0.z, a0.w, a1.x, a1.y, a1.z, a1.w};
            float wv[8] = {w0.x, w0.y, w0.z, w0.w, w1.x, w1.y, w1.z, w1.w};
#pragma unroll
            for (int i = 0; i < 8; ++i)
#pragma unroll
                for (int j = 0; j < 8; ++j) c[i][j] += wv[i] * av[j];
        }
    }
#pragma unroll
    for (int i = 0; i < 8; ++i) {
        const int f = f0 + ((i < 4) ? ty * 4 + i : 64 + ty * 4 + (i - 4));
        const float bvv = bias[f];
        float* row = out + ((size_t)b * E_DIM + f) * L_SEQ + l0;
        float4 o0, o1;
        o0.x = c[i][0] + bvv; o0.y = c[i][1] + bvv;
        o0.z = c[i][2] + bvv; o0.w = c[i][3] + bvv;
        o1.x = c[i][4] + bvv; o1.y = c[i][5] + bvv;
        o1.z = c[i][6] + bvv; o1.w = c[i][7] + bvv;
        *(float4*)(row + tx * 4) = o0;
        *(float4*)(row + 64 + tx * 4) = o1;
    }
}

// ---------------------------------------------------------------------------
extern "C" void kernel_launch(void* const* d_in, const int* in_sizes, int n_in,
                              void* d_out, int out_size, void* d_ws, size_t ws_size,
                              hipStream_t stream) {
    const float* query = (const float*)d_in[0];
    const float* keys  = (const float*)d_in[1];
    const float* vals  = (const float*)d_in[2];
    const int*   rind  = (const int*)d_in[3];
    const float* ipw   = (const float*)d_in[4];
    const float* ipb   = (const float*)d_in[5];
    const float* opw   = (const float*)d_in[6];
    const float* opb   = (const float*)d_in[7];
    float* out = (float*)d_out;

    char* ws = (char*)d_ws;
    float*  qs_pack = (float*)(ws + 0);                         //  2 MiB [b][s][e]
    double* minpart = (double*)(ws + (size_t)2  * 1024 * 1024); //  1 MiB
    int*    sel     = (int*)   (ws + (size_t)3  * 1024 * 1024); //  8 KiB
    short*  khb     = (short*) (ws + (size_t)4  * 1024 * 1024); //  1 MiB bf16
    short*  vtb     = (short*) (ws + (size_t)6  * 1024 * 1024); //  1 MiB bf16
    short*  qhb     = (short*) (ws + (size_t)8  * 1024 * 1024); // 16 MiB bf16
    float*  obuf    = (float*) (ws + (size_t)40 * 1024 * 1024); // 32 MiB

    const float scale = 0.17677669529663687f;  // 32^-0.5

    k_gather<<<dim3((B_SZ * E_DIM * S_TOP) / 256), 256, 0, stream>>>(query, rind, qs_pack);
    k_dist<<<dim3(L_SEQ / 64, NSPLIT, B_SZ), dim3(64, 4), 0, stream>>>(keys, qs_pack, minpart);
    k_rank<<<dim3(L_SEQ / 256, B_SZ), 256, 0, stream>>>(minpart, sel);
    k_kvproj<0><<<dim3(E_DIM / 64, S_TOP / 64, B_SZ), dim3(16, 16), 0, stream>>>(
        keys, sel, ipw + (size_t)E_DIM * E_DIM, ipb + E_DIM, khb);
    k_kvproj<1><<<dim3(E_DIM / 64, S_TOP / 64, B_SZ), dim3(16, 16), 0, stream>>>(
        vals, sel, ipw + (size_t)2 * E_DIM * E_DIM, ipb + 2 * E_DIM, vtb);
    k_qproj<<<dim3(E_DIM / 128, L_SEQ / 128, B_SZ), dim3(16, 16), 0, stream>>>(
        query, ipw, ipb, qhb, scale);
    k_attn<<<dim3(L_SEQ / 64, NHEAD, B_SZ), 256, 0, stream>>>(qhb, khb, vtb, obuf);
    k_outproj<<<dim3(L_SEQ / 128, E_DIM / 128, B_SZ), dim3(16, 16), 0, stream>>>(
        obuf, opw, opb, out);
}

// Round 6
// 548.287 us; speedup vs baseline: 2.0511x; 1.1539x over previous
//
#include <hip/hip_runtime.h>
#include <math.h>

#define B_SZ   8
#define E_DIM  256
#define L_SEQ  4096
#define S_TOP  256
#define NHEAD  8
#define HD     32
#define NSPLIT 4   // s-blocks in distance kernel (S_TOP/64)
#define JSPL   8   // j-splits in rank kernel

typedef __attribute__((ext_vector_type(8))) short bf16x8;   // MFMA A/B frag
typedef __attribute__((ext_vector_type(4))) float f32x4;    // MFMA C/D frag

// round-to-nearest-even fp32 -> bf16 (values finite here)
__device__ inline short f2bf(float x) {
    union { float f; unsigned u; } v; v.f = x;
    unsigned r = (v.u + 0x7fff + ((v.u >> 16) & 1)) >> 16;
    return (short)r;
}

// ---------------------------------------------------------------------------
// K0: gather query subset, TRANSPOSED layout: qs_pack[b][s][e]
// ---------------------------------------------------------------------------
__global__ __launch_bounds__(256) void k_gather(const float* __restrict__ query,
                                                const int* __restrict__ ind,
                                                float* __restrict__ qs_pack) {
    int t = blockIdx.x * 256 + threadIdx.x;     // over B*S*E = 524288
    int e = t & (E_DIM - 1);
    int s = (t >> 8) & (S_TOP - 1);
    int b = t >> 16;
    int idx = ind[b * S_TOP + s];
    qs_pack[t] = query[((size_t)b * E_DIM + e) * L_SEQ + idx];
}

// ---------------------------------------------------------------------------
// K1: keys-in-registers L1-distance + min (round-5 structure, unchanged).
// Numerics: per (l,s), fp32 sum over ascending 32-e chunks, each chunk
// folded into f64 ascending, exact f64 min. grid (L/64, NSPLIT, B).
// ---------------------------------------------------------------------------
__global__ __launch_bounds__(256) void k_dist(const float* __restrict__ keys,
                                              const float* __restrict__ qs_pack,
                                              double* __restrict__ minpart) {
    const int b    = blockIdx.z;
    const int ss   = blockIdx.y;                // s-slice [ss*64, ss*64+64)
    const int l0   = blockIdx.x * 64;
    const int lane = threadIdx.x;               // 0..63 : l
    const int sg   = threadIdx.y;               // 0..3  : s-group of 16
    const int lid  = sg * 64 + lane;
    __shared__ float  Ks[32][64];               // [e][l]  8 KiB
    __shared__ float  Qs[64][36];               // [s][e]  9 KiB
    __shared__ double red[4][64];               // cross-sg min, 2 KiB
    const float* kb = keys + (size_t)b * E_DIM * L_SEQ + l0;
    const float* qb = qs_pack + ((size_t)b * S_TOP + ss * 64) * E_DIM;

    double d[16];
#pragma unroll
    for (int j = 0; j < 16; ++j) d[j] = 0.0;

    for (int c0 = 0; c0 < E_DIM; c0 += 32) {
        __syncthreads();
#pragma unroll
        for (int r = 0; r < 2; ++r) {           // stage 512+512 float4
            int f4 = lid + 256 * r;
            int e  = f4 >> 4, l4 = (f4 & 15) * 4;
            *(float4*)&Ks[e][l4] = *(const float4*)(kb + (size_t)(c0 + e) * L_SEQ + l4);
            int s  = f4 >> 3, e4 = (f4 & 7) * 4;
            *(float4*)&Qs[s][e4] = *(const float4*)(qb + (size_t)s * E_DIM + c0 + e4);
        }
        __syncthreads();
        float kr[32];
#pragma unroll
        for (int e = 0; e < 32; ++e) kr[e] = Ks[e][lane];   // 2-way, free
#pragma unroll
        for (int si = 0; si < 16; ++si) {
            const float* qrow = &Qs[sg * 16 + si][0];       // wave-broadcast
            float csum = 0.f;
#pragma unroll
            for (int e = 0; e < 32; ++e) csum += fabsf(kr[e] - qrow[e]);
            d[si] += (double)csum;
        }
    }
    double md = d[0];
#pragma unroll
    for (int j = 1; j < 16; ++j) md = fmin(md, d[j]);
    red[sg][lane] = md;
    __syncthreads();
    if (sg == 0) {
        double m = red[0][lane];
        m = fmin(m, red[1][lane]);
        m = fmin(m, red[2][lane]);
        m = fmin(m, red[3][lane]);
        minpart[((size_t)(b * NSPLIT + ss)) * L_SEQ + l0 + lane] = m;
    }
}

// ---------------------------------------------------------------------------
// K2a (round-6): partial rank over a 512-j chunk. Round-5 k_rank was
// parallelism-starved (128 blocks, 5.4% occupancy, 139us). Grid
// (L/256, JSPL, B) = 1024 blocks. Stages the j-chunk (4-split min fused into
// staging) in LDS; each thread counts its l against 512 j's. Sum of disjoint
// partial counts of the identical exact predicate == round-5 rank.
// ---------------------------------------------------------------------------
__global__ __launch_bounds__(256) void k_rankpart(const double* __restrict__ minpart,
                                                  int* __restrict__ rankpart) {
    const int b  = blockIdx.z;
    const int js = blockIdx.y;                  // j-chunk [js*512, +512)
    const int l  = blockIdx.x * 256 + threadIdx.x;
    __shared__ double sd[512];                  // 4 KiB
    const double* mp = minpart + (size_t)b * NSPLIT * L_SEQ;
    for (int jj = threadIdx.x; jj < 512; jj += 256) {
        const int j = js * 512 + jj;
        double v = mp[j];
        v = fmin(v, mp[L_SEQ + j]);
        v = fmin(v, mp[2 * L_SEQ + j]);
        v = fmin(v, mp[3 * L_SEQ + j]);
        sd[jj] = v;
    }
    double dl = mp[l];
    dl = fmin(dl, mp[L_SEQ + l]);
    dl = fmin(dl, mp[2 * L_SEQ + l]);
    dl = fmin(dl, mp[3 * L_SEQ + l]);
    __syncthreads();
    const int jbase = js * 512;
    int rank = 0;
#pragma unroll 8
    for (int jj = 0; jj < 512; ++jj) {
        double dj = sd[jj];
        rank += (dj < dl) || (dj == dl && (jbase + jj) < l) ? 1 : 0;
    }
    rankpart[((size_t)(b * JSPL + js)) * L_SEQ + l] = rank;
}

// ---------------------------------------------------------------------------
// K2b: combine partial ranks, scatter selected indices (rank < 256).
// ---------------------------------------------------------------------------
__global__ __launch_bounds__(256) void k_sel(const int* __restrict__ rankpart,
                                             int* __restrict__ sel) {
    const int t = blockIdx.x * 256 + threadIdx.x;   // over B*L
    const int b = t >> 12;
    const int l = t & (L_SEQ - 1);
    int r = 0;
#pragma unroll
    for (int s = 0; s < JSPL; ++s)
        r += rankpart[((size_t)(b * JSPL + s)) * L_SEQ + l];
    if (r < S_TOP) sel[b * S_TOP + r] = l;
}

// ---------------------------------------------------------------------------
// K3: gather + project selected keys/values -> bf16 outputs for MFMA attn.
// TR=0 (keys):   dst[b][k][f] bf16
// TR=1 (values): dst[b][f][k] bf16 (transposed so PV B-frags are contiguous)
// grid (E/64, S_TOP/64, B), block (16,16), 4x4 micro-tile
// ---------------------------------------------------------------------------
template <int TR>
__global__ __launch_bounds__(256) void k_kvproj(const float* __restrict__ src,
                                                const int* __restrict__ sel,
                                                const float* __restrict__ W,
                                                const float* __restrict__ bias,
                                                short* __restrict__ dst) {
    const int b  = blockIdx.z;
    const int f0 = blockIdx.x * 64;
    const int k0 = blockIdx.y * 64;
    const int tx = threadIdx.x, ty = threadIdx.y;
    const int lid = ty * 16 + tx;
    __shared__ float As[16][68];
    __shared__ float Ws[16][68];
    float c[4][4] = {};
    const float* sb = src + (size_t)b * E_DIM * L_SEQ;
    const int* selb = sel + b * S_TOP;
    for (int e0 = 0; e0 < E_DIM; e0 += 16) {
        {   // As[e][k] gather (scattered loads)
            int e  = lid >> 4;
            int k4 = (lid & 15) * 4;
#pragma unroll
            for (int c2 = 0; c2 < 4; ++c2) {
                int kk = k4 + c2;
                As[e][kk] = sb[(size_t)(e0 + e) * L_SEQ + selb[k0 + kk]];
            }
        }
        {   // Ws[e][f] from row-major W[f][e]
            int f  = lid >> 2;
            int e4 = (lid & 3) * 4;
            float4 w = *(const float4*)(W + (size_t)(f0 + f) * E_DIM + e0 + e4);
            Ws[e4 + 0][f] = w.x; Ws[e4 + 1][f] = w.y;
            Ws[e4 + 2][f] = w.z; Ws[e4 + 3][f] = w.w;
        }
        __syncthreads();
#pragma unroll
        for (int e = 0; e < 16; ++e) {
            float4 a = *(const float4*)&As[e][ty * 4];
            float4 w = *(const float4*)&Ws[e][tx * 4];
            float av[4] = {a.x, a.y, a.z, a.w};
            float wv[4] = {w.x, w.y, w.z, w.w};
#pragma unroll
            for (int i = 0; i < 4; ++i)
#pragma unroll
                for (int j = 0; j < 4; ++j) c[i][j] += av[i] * wv[j];
        }
        __syncthreads();
    }
    if (TR == 0) {
#pragma unroll
        for (int i = 0; i < 4; ++i) {
            short4 o;
            o.x = f2bf(c[i][0] + bias[f0 + tx * 4 + 0]);
            o.y = f2bf(c[i][1] + bias[f0 + tx * 4 + 1]);
            o.z = f2bf(c[i][2] + bias[f0 + tx * 4 + 2]);
            o.w = f2bf(c[i][3] + bias[f0 + tx * 4 + 3]);
            *(short4*)(dst + ((size_t)b * S_TOP + k0 + ty * 4 + i) * E_DIM + f0 + tx * 4) = o;
        }
    } else {
#pragma unroll
        for (int j = 0; j < 4; ++j) {
            const float bv = bias[f0 + tx * 4 + j];
            short4 o;
            o.x = f2bf(c[0][j] + bv); o.y = f2bf(c[1][j] + bv);
            o.z = f2bf(c[2][j] + bv); o.w = f2bf(c[3][j] + bv);
            *(short4*)(dst + ((size_t)b * E_DIM + f0 + tx * 4 + j) * S_TOP + k0 + ty * 4) = o;
        }
    }
}

// ---------------------------------------------------------------------------
// K3q: Q projection, 128x128 tile, 8x8 micro-tile (round-5, unchanged).
// grid (E/128, L/128, B), block (16,16)
// ---------------------------------------------------------------------------
__global__ __launch_bounds__(256) void k_qproj(const float* __restrict__ query,
                                               const float* __restrict__ W,
                                               const float* __restrict__ bias,
                                               short* __restrict__ qhb,
                                               float scale) {
    const int b  = blockIdx.z;
    const int f0 = blockIdx.x * 128;
    const int l0 = blockIdx.y * 128;
    const int tx = threadIdx.x, ty = threadIdx.y;
    const int lid = ty * 16 + tx;
    __shared__ float As[8][132];                // [e][l]
    __shared__ float Ws[8][132];                // [e][f]
    float c[8][8] = {};
    const float* sb = query + (size_t)b * E_DIM * L_SEQ + l0;
    for (int e0 = 0; e0 < E_DIM; e0 += 8) {
        __syncthreads();
        {
            int e  = lid >> 5, l4 = (lid & 31) * 4;
            *(float4*)&As[e][l4] = *(const float4*)(sb + (size_t)(e0 + e) * L_SEQ + l4);
            int f  = lid >> 1, e4 = (lid & 1) * 4;
            float4 w = *(const float4*)(W + (size_t)(f0 + f) * E_DIM + e0 + e4);
            Ws[e4 + 0][f] = w.x; Ws[e4 + 1][f] = w.y;
            Ws[e4 + 2][f] = w.z; Ws[e4 + 3][f] = w.w;
        }
        __syncthreads();
#pragma unroll
        for (int e = 0; e < 8; ++e) {
            float4 a0 = *(const float4*)&As[e][tx * 4];
            float4 a1 = *(const float4*)&As[e][64 + tx * 4];
            float4 w0 = *(const float4*)&Ws[e][ty * 4];
            float4 w1 = *(const float4*)&Ws[e][64 + ty * 4];
            float av[8] = {a0.x, a0.y, a0.z, a0.w, a1.x, a1.y, a1.z, a1.w};
            float wv[8] = {w0.x, w0.y, w0.z, w0.w, w1.x, w1.y, w1.z, w1.w};
#pragma unroll
            for (int i = 0; i < 8; ++i)
#pragma unroll
                for (int j = 0; j < 8; ++j) c[i][j] += av[i] * wv[j];
        }
    }
    float bv[8];
#pragma unroll
    for (int j = 0; j < 8; ++j)
        bv[j] = bias[f0 + ((j < 4) ? ty * 4 + j : 64 + ty * 4 + (j - 4))];
#pragma unroll
    for (int i = 0; i < 8; ++i) {
        const int l = l0 + ((i < 4) ? tx * 4 + i : 64 + tx * 4 + (i - 4));
        short* row = qhb + ((size_t)b * L_SEQ + l) * E_DIM + f0;
        short4 o0, o1;
        o0.x = f2bf(scale * (c[i][0] + bv[0]));
        o0.y = f2bf(scale * (c[i][1] + bv[1]));
        o0.z = f2bf(scale * (c[i][2] + bv[2]));
        o0.w = f2bf(scale * (c[i][3] + bv[3]));
        o1.x = f2bf(scale * (c[i][4] + bv[4]));
        o1.y = f2bf(scale * (c[i][5] + bv[5]));
        o1.z = f2bf(scale * (c[i][6] + bv[6]));
        o1.w = f2bf(scale * (c[i][7] + bv[7]));
        *(short4*)(row + ty * 4) = o0;
        *(short4*)(row + 64 + ty * 4) = o1;
    }
}

// ---------------------------------------------------------------------------
// K4: bf16 MFMA flash attention (round-4 structure, unchanged).
// grid (L/64, H, B), block 256 (4 waves).
// ---------------------------------------------------------------------------
__global__ __launch_bounds__(256) void k_attn(const short* __restrict__ qhb,
                                              const short* __restrict__ khb,
                                              const short* __restrict__ vtb,
                                              float* __restrict__ ob) {
    __shared__ short P[4][16][264];             // 33 KB, wave-private slices
    const int b = blockIdx.z, h = blockIdx.y;
    const int wv   = threadIdx.x >> 6;
    const int lane = threadIdx.x & 63;
    const int quad = lane >> 4;
    const int m    = lane & 15;
    const int l0 = blockIdx.x * 64 + wv * 16;

    const short* qp = qhb + ((size_t)b * L_SEQ + l0 + m) * E_DIM + h * HD + quad * 8;
    const bf16x8 qa = *(const bf16x8*)qp;

    const short* kb = khb + (size_t)b * S_TOP * E_DIM + h * HD + quad * 8;
    f32x4 sacc[16];
    const f32x4 zero = {0.f, 0.f, 0.f, 0.f};
#pragma unroll
    for (int t = 0; t < 16; ++t) {
        bf16x8 kf = *(const bf16x8*)(kb + (size_t)(t * 16 + m) * E_DIM);
        sacc[t] = __builtin_amdgcn_mfma_f32_16x16x32_bf16(qa, kf, zero, 0, 0, 0);
    }

    float mx[4], ssum[4];
#pragma unroll
    for (int r = 0; r < 4; ++r) {
        float v = sacc[0][r];
#pragma unroll
        for (int t = 1; t < 16; ++t) v = fmaxf(v, sacc[t][r]);
#pragma unroll
        for (int off = 1; off < 16; off <<= 1) v = fmaxf(v, __shfl_xor(v, off, 16));
        mx[r] = v;
        ssum[r] = 0.f;
    }
#pragma unroll
    for (int t = 0; t < 16; ++t) {
#pragma unroll
        for (int r = 0; r < 4; ++r) {
            float p = __expf(sacc[t][r] - mx[r]);
            ssum[r] += p;
            P[wv][quad * 4 + r][t * 16 + m] = f2bf(p);
        }
    }
#pragma unroll
    for (int r = 0; r < 4; ++r) {
        float v = ssum[r];
#pragma unroll
        for (int off = 1; off < 16; off <<= 1) v += __shfl_xor(v, off, 16);
        ssum[r] = v;
    }

    const short* vb = vtb + ((size_t)b * E_DIM + h * HD) * S_TOP;
    f32x4 oacc[2];
#pragma unroll
    for (int dt = 0; dt < 2; ++dt) {
        f32x4 acc = zero;
#pragma unroll
        for (int k0 = 0; k0 < S_TOP; k0 += 32) {
            bf16x8 pa = *(const bf16x8*)&P[wv][m][k0 + quad * 8];
            bf16x8 vf = *(const bf16x8*)(vb + (size_t)(dt * 16 + m) * S_TOP + k0 + quad * 8);
            acc = __builtin_amdgcn_mfma_f32_16x16x32_bf16(pa, vf, acc, 0, 0, 0);
        }
        oacc[dt] = acc;
    }

    float* op = ob + ((size_t)b * L_SEQ + l0) * E_DIM + h * HD;
#pragma unroll
    for (int r = 0; r < 4; ++r) {
        const float inv = 1.0f / ssum[r];
#pragma unroll
        for (int dt = 0; dt < 2; ++dt)
            op[(size_t)(quad * 4 + r) * E_DIM + dt * 16 + m] = oacc[dt][r] * inv;
    }
}

// ---------------------------------------------------------------------------
// K5: out projection, 128x128 tile, 8x8 micro-tile (round-5, unchanged).
// grid (L/128, E/128, B), block (16,16)
// ---------------------------------------------------------------------------
__global__ __launch_bounds__(256) void k_outproj(const float* __restrict__ ob,
                                                 const float* __restrict__ W,
                                                 const float* __restrict__ bias,
                                                 float* __restrict__ out) {
    const int b  = blockIdx.z;
    const int l0 = blockIdx.x * 128;
    const int f0 = blockIdx.y * 128;
    const int tx = threadIdx.x, ty = threadIdx.y;
    const int lid = ty * 16 + tx;
    __shared__ float As[8][132];                // [e][l]
    __shared__ float Ws[8][132];                // [e][f]
    float c[8][8] = {};
    const float* sb = ob + (size_t)b * L_SEQ * E_DIM;
    for (int e0 = 0; e0 < E_DIM; e0 += 8) {
        __syncthreads();
        {
            int l  = lid >> 1, e4 = (lid & 1) * 4;
            float4 a = *(const float4*)(sb + (size_t)(l0 + l) * E_DIM + e0 + e4);
            As[e4 + 0][l] = a.x; As[e4 + 1][l] = a.y;
            As[e4 + 2][l] = a.z; As[e4 + 3][l] = a.w;
            int f  = lid >> 1, e4w = (lid & 1) * 4;
            float4 w = *(const float4*)(W + (size_t)(f0 + f) * E_DIM + e0 + e4w);
            Ws[e4w + 0][f] = w.x; Ws[e4w + 1][f] = w.y;
            Ws[e4w + 2][f] = w.z; Ws[e4w + 3][f] = w.w;
        }
        __syncthreads();
#pragma unroll
        for (int e = 0; e < 8; ++e) {
            float4 a0 = *(const float4*)&As[e][tx * 4];
            float4 a1 = *(const float4*)&As[e][64 + tx * 4];
            float4 w0 = *(const float4*)&Ws[e][ty * 4];
            float4 w1 = *(const float4*)&Ws[e][64 + ty * 4];
            float av[8] = {a0.x, a0.y, a0.z, a0.w, a1.x, a1.y, a1.z, a1.w};
            float wv[8] = {w0.x, w0.y, w0.z, w0.w, w1.x, w1.y, w1.z, w1.w};
#pragma unroll
            for (int i = 0; i < 8; ++i)
#pragma unroll
                for (int j = 0; j < 8; ++j) c[i][j] += wv[i] * av[j];
        }
    }
#pragma unroll
    for (int i = 0; i < 8; ++i) {
        const int f = f0 + ((i < 4) ? ty * 4 + i : 64 + ty * 4 + (i - 4));
        const float bvv = bias[f];
        float* row = out + ((size_t)b * E_DIM + f) * L_SEQ + l0;
        float4 o0, o1;
        o0.x = c[i][0] + bvv; o0.y = c[i][1] + bvv;
        o0.z = c[i][2] + bvv; o0.w = c[i][3] + bvv;
        o1.x = c[i][4] + bvv; o1.y = c[i][5] + bvv;
        o1.z = c[i][6] + bvv; o1.w = c[i][7] + bvv;
        *(float4*)(row + tx * 4) = o0;
        *(float4*)(row + 64 + tx * 4) = o1;
    }
}

// ---------------------------------------------------------------------------
extern "C" void kernel_launch(void* const* d_in, const int* in_sizes, int n_in,
                              void* d_out, int out_size, void* d_ws, size_t ws_size,
                              hipStream_t stream) {
    const float* query = (const float*)d_in[0];
    const float* keys  = (const float*)d_in[1];
    const float* vals  = (const float*)d_in[2];
    const int*   rind  = (const int*)d_in[3];
    const float* ipw   = (const float*)d_in[4];
    const float* ipb   = (const float*)d_in[5];
    const float* opw   = (const float*)d_in[6];
    const float* opb   = (const float*)d_in[7];
    float* out = (float*)d_out;

    char* ws = (char*)d_ws;
    float*  qs_pack  = (float*)(ws + 0);                         //  2 MiB [b][s][e]
    double* minpart  = (double*)(ws + (size_t)2  * 1024 * 1024); //  1 MiB
    int*    sel      = (int*)   (ws + (size_t)3  * 1024 * 1024); //  8 KiB
    short*  khb      = (short*) (ws + (size_t)4  * 1024 * 1024); //  1 MiB bf16
    int*    rankpart = (int*)   (ws + (size_t)5  * 1024 * 1024); //  1 MiB
    short*  vtb      = (short*) (ws + (size_t)6  * 1024 * 1024); //  1 MiB bf16
    short*  qhb      = (short*) (ws + (size_t)8  * 1024 * 1024); // 16 MiB bf16
    float*  obuf     = (float*) (ws + (size_t)40 * 1024 * 1024); // 32 MiB

    const float scale = 0.17677669529663687f;  // 32^-0.5

    k_gather<<<dim3((B_SZ * E_DIM * S_TOP) / 256), 256, 0, stream>>>(query, rind, qs_pack);
    k_dist<<<dim3(L_SEQ / 64, NSPLIT, B_SZ), dim3(64, 4), 0, stream>>>(keys, qs_pack, minpart);
    k_rankpart<<<dim3(L_SEQ / 256, JSPL, B_SZ), 256, 0, stream>>>(minpart, rankpart);
    k_sel<<<dim3((B_SZ * L_SEQ) / 256), 256, 0, stream>>>(rankpart, sel);
    k_kvproj<0><<<dim3(E_DIM / 64, S_TOP / 64, B_SZ), dim3(16, 16), 0, stream>>>(
        keys, sel, ipw + (size_t)E_DIM * E_DIM, ipb + E_DIM, khb);
    k_kvproj<1><<<dim3(E_DIM / 64, S_TOP / 64, B_SZ), dim3(16, 16), 0, stream>>>(
        vals, sel, ipw + (size_t)2 * E_DIM * E_DIM, ipb + 2 * E_DIM, vtb);
    k_qproj<<<dim3(E_DIM / 128, L_SEQ / 128, B_SZ), dim3(16, 16), 0, stream>>>(
        query, ipw, ipb, qhb, scale);
    k_attn<<<dim3(L_SEQ / 64, NHEAD, B_SZ), 256, 0, stream>>>(qhb, khb, vtb, obuf);
    k_outproj<<<dim3(L_SEQ / 128, E_DIM / 128, B_SZ), dim3(16, 16), 0, stream>>>(
        obuf, opw, opb, out);
}